// Round 5
// baseline (190.795 us; speedup 1.0000x reference)
//
#include <hip/hip_runtime.h>
#include <hip/hip_bf16.h>
#include <stdint.h>

typedef __bf16 bf16_t;
typedef __bf16 bf16x8 __attribute__((ext_vector_type(8)));
typedef float f32x4 __attribute__((ext_vector_type(4)));

#define DEVI __device__ __forceinline__

constexpr int BB = 2;       // batch
constexpr int SS = 4096;    // seq
constexpr int EE = 1024;    // embed
constexpr int HH = 16;      // heads
constexpr int DD = 64;      // head dim
constexpr int MM = BB * SS; // 8192 token rows

// async global->LDS, 16B per lane; LDS dest must be wave-uniform base (HW adds lane*16)
DEVI void gload16(const void* g, void* l) {
  __builtin_amdgcn_global_load_lds(
      (const __attribute__((address_space(1))) void*)g,
      (__attribute__((address_space(3))) void*)l, 16, 0, 0);
}

// ---------------- f32 -> bf16 convert (vectorized 8/thread) ----------------
__global__ void cvt_kernel(const float* __restrict__ in, bf16_t* __restrict__ out, int n8) {
  int i = blockIdx.x * 256 + threadIdx.x;
  if (i >= n8) return;
  const float* p = in + (size_t)i * 8;
  bf16x8 o;
#pragma unroll
  for (int j = 0; j < 8; ++j) o[j] = (bf16_t)p[j];
  *(bf16x8*)(out + (size_t)i * 8) = o;
}

// ---------------- weight transpose + cvt: W[k][n] f32 -> WT[n][k] bf16 ----------------
__global__ void wt_kernel(const float* __restrict__ w0, const float* __restrict__ w1,
                          const float* __restrict__ w2, const float* __restrict__ w3,
                          const float* __restrict__ w4, bf16_t* __restrict__ out) {
  __shared__ float tile[32][33];
  const float* Wsel = blockIdx.z == 0 ? w0 : blockIdx.z == 1 ? w1 :
                      blockIdx.z == 2 ? w2 : blockIdx.z == 3 ? w3 : w4;
  bf16_t* O = out + (size_t)blockIdx.z * EE * EE;
  int n0 = blockIdx.x * 32, k0 = blockIdx.y * 32;
  int tx = threadIdx.x & 31, ty = threadIdx.x >> 5;
#pragma unroll
  for (int i = 0; i < 4; ++i)
    tile[ty + i * 8][tx] = Wsel[(size_t)(k0 + ty + i * 8) * EE + n0 + tx];
  __syncthreads();
#pragma unroll
  for (int i = 0; i < 4; ++i)
    O[(size_t)(n0 + ty + i * 8) * EE + k0 + tx] = (bf16_t)tile[tx][ty + i * 8];
}

// ---------------- GEMM: C[M][N] = A[M][K] @ Bt[N][K]^T, 128x128 tile, BK=64 ----------------
// m97-style 2-barrier structure (proven 825 TF on this shape; 2-3 blocks/CU implicit overlap).
// MODE 0: QKVG — bf16 out into 4 contiguous regions; widx uniform per block (n0>>10).
//         widx<=1 (Q,K): RoPE applied in-register. widx==2 (V): transposed [B][H][D][S].
// MODE 1: f32 out [M][1024] (final projection).
template <int MODE>
__global__ __launch_bounds__(256) void gemm_bt(const bf16_t* __restrict__ A,
                                               const bf16_t* __restrict__ Bt,
                                               void* __restrict__ Cout,
                                               const float* __restrict__ cosp,
                                               const float* __restrict__ sinp) {
  __shared__ bf16_t Al[128 * 64];
  __shared__ bf16_t Bl[128 * 64];
  const int m0 = blockIdx.x * 128;
  const int n0 = blockIdx.y * 128;
  const int tid = threadIdx.x;
  const int wv = tid >> 6, ln = tid & 63;
  const int wm = wv >> 1, wn = wv & 1;
  f32x4 acc[4][4] = {};

  for (int k0 = 0; k0 < EE; k0 += 64) {
    __syncthreads();  // prior iter's LDS readers done before overwrite
#pragma unroll
    for (int i = 0; i < 4; ++i) {
      int slot = i * 256 + wv * 64 + ln;  // 16B slots, 8 per 128B row
      int r = slot >> 3, c = slot & 7;
      int cs = c ^ (r & 7);  // inverse-swizzled source chunk (linear LDS dest)
      gload16(A + (size_t)(m0 + r) * EE + k0 + cs * 8, Al + (size_t)(i * 256 + wv * 64) * 8);
      gload16(Bt + (size_t)(n0 + r) * EE + k0 + cs * 8, Bl + (size_t)(i * 256 + wv * 64) * 8);
    }
    __syncthreads();  // compiler drains vmcnt(0) before barrier
#pragma unroll
    for (int kk = 0; kk < 2; ++kk) {
      bf16x8 af[4], bfr[4];
#pragma unroll
      for (int mi = 0; mi < 4; ++mi) {
        int row = wm * 64 + mi * 16 + (ln & 15);
        int ch = (kk * 4 + (ln >> 4)) ^ (row & 7);
        af[mi] = *(const bf16x8*)(Al + row * 64 + ch * 8);
      }
#pragma unroll
      for (int ni = 0; ni < 4; ++ni) {
        int row = wn * 64 + ni * 16 + (ln & 15);
        int ch = (kk * 4 + (ln >> 4)) ^ (row & 7);
        bfr[ni] = *(const bf16x8*)(Bl + row * 64 + ch * 8);
      }
#pragma unroll
      for (int mi = 0; mi < 4; ++mi)
#pragma unroll
        for (int ni = 0; ni < 4; ++ni)
          acc[mi][ni] = __builtin_amdgcn_mfma_f32_16x16x32_bf16(af[mi], bfr[ni], acc[mi][ni], 0, 0, 0);
    }
  }

  if (MODE == 0) {
    // widx uniform per block; wave's 64-col span = exactly one head for Q/K RoPE pairing
    const int widx = n0 >> 10;
    const int cb = (n0 & 1023) + wn * 64;  // region-local col base (head-aligned)
    bf16_t* W = (bf16_t*)Cout + (size_t)widx * MM * EE;
    if (widx <= 1) {
      // RoPE in-register: d = ni*16+(ln&15) in [0,64); partner d^32 = acc[mi][ni^2] (same lane)
#pragma unroll
      for (int mi = 0; mi < 4; ++mi) {
#pragma unroll
        for (int r = 0; r < 4; ++r) {
          int row = m0 + wm * 64 + mi * 16 + ((ln >> 4) << 2) + r;
          int s = row & (SS - 1);
          float cv[4], sv[4];
#pragma unroll
          for (int ni = 0; ni < 4; ++ni) {
            int d = ni * 16 + (ln & 15);
            cv[ni] = cosp[s * DD + d];
            sv[ni] = sinp[s * DD + d];
          }
#pragma unroll
          for (int ni = 0; ni < 4; ++ni) {
            float v = acc[mi][ni][r], p = acc[mi][ni ^ 2][r];
            float o = v * cv[ni] + (ni < 2 ? -p : p) * sv[ni];
            W[(size_t)row * EE + cb + ni * 16 + (ln & 15)] = (bf16_t)o;
          }
        }
      }
    } else if (widx == 2) {  // V: write transposed [B][H][D][S]
#pragma unroll
      for (int mi = 0; mi < 4; ++mi)
#pragma unroll
        for (int ni = 0; ni < 4; ++ni) {
          int row = m0 + wm * 64 + mi * 16 + ((ln >> 4) << 2);
          int ncol = cb + ni * 16 + (ln & 15);
          int h = ncol >> 6, d = ncol & 63;
          int b = row >> 12, s = row & (SS - 1);
          bf16_t* p = W + (((size_t)b * HH + h) * DD + d) * SS + s;
#pragma unroll
          for (int r = 0; r < 4; ++r) p[r] = (bf16_t)acc[mi][ni][r];
        }
    } else {  // gate
#pragma unroll
      for (int mi = 0; mi < 4; ++mi)
#pragma unroll
        for (int ni = 0; ni < 4; ++ni) {
          int row = m0 + wm * 64 + mi * 16 + ((ln >> 4) << 2);
          bf16_t* p = W + (size_t)row * EE + cb + ni * 16 + (ln & 15);
#pragma unroll
          for (int r = 0; r < 4; ++r) p[(size_t)r * EE] = (bf16_t)acc[mi][ni][r];
        }
    }
  } else {
    float* O = (float*)Cout;
#pragma unroll
    for (int mi = 0; mi < 4; ++mi)
#pragma unroll
      for (int ni = 0; ni < 4; ++ni) {
        int row = m0 + wm * 64 + mi * 16 + ((ln >> 4) << 2);
        int col = n0 + wn * 64 + ni * 16 + (ln & 15);
#pragma unroll
        for (int r = 0; r < 4; ++r) O[(size_t)(row + r) * EE + col] = acc[mi][ni][r];
      }
  }
}

// ---------------- block-diagonal attention + fused sigmoid gate ----------------
// grid: B*nb*H blocks; 4 waves; K/V double-buffered, prefetch kc+1 before compute kc.
__global__ __launch_bounds__(256) void attn_kernel(const bf16_t* __restrict__ Q,
                                                   const bf16_t* __restrict__ Kc,
                                                   const bf16_t* __restrict__ Vt,
                                                   const bf16_t* __restrict__ G,
                                                   bf16_t* __restrict__ AO) {
  __shared__ bf16_t Kl[2][64 * 64];
  __shared__ bf16_t Vl[2][64 * 64];
  __shared__ bf16_t Pl[4][64 * 64];
  const int bx = blockIdx.x;
  const int h = bx & 15, sb = (bx >> 4) & 15, b = bx >> 8;
  const int tid = threadIdx.x, wv = tid >> 6, ln = tid & 63;
  const int qrow0 = b * SS + sb * 256 + wv * 64;

  bf16x8 qf[4][2];
#pragma unroll
  for (int mi = 0; mi < 4; ++mi)
#pragma unroll
    for (int kk = 0; kk < 2; ++kk)
      qf[mi][kk] = *(const bf16x8*)(Q + (size_t)(qrow0 + mi * 16 + (ln & 15)) * EE +
                                    h * DD + kk * 32 + ((ln >> 4) << 3));

  f32x4 o[4][4] = {};
  float mr[4][4], lr[4][4];
#pragma unroll
  for (int i = 0; i < 4; ++i)
#pragma unroll
    for (int r = 0; r < 4; ++r) { mr[i][r] = -1e30f; lr[i][r] = 0.f; }

#define STAGE_KV(KC, BI) do {                                                        \
    const int krow0_ = b * SS + sb * 256 + (KC) * 64;                                \
    _Pragma("unroll") for (int i_ = 0; i_ < 2; ++i_) {                               \
      int slot_ = i_ * 256 + wv * 64 + ln;                                           \
      int r_ = slot_ >> 3, c_ = slot_ & 7, cs_ = c_ ^ (r_ & 7);                      \
      gload16(Kc + (size_t)(krow0_ + r_) * EE + h * DD + cs_ * 8,                    \
              &Kl[BI][(i_ * 256 + wv * 64) * 8]);                                    \
      gload16(Vt + (((size_t)b * HH + h) * DD + r_) * SS + sb * 256 + (KC) * 64 +    \
                  cs_ * 8,                                                           \
              &Vl[BI][(i_ * 256 + wv * 64) * 8]);                                    \
    }                                                                                \
  } while (0)

  STAGE_KV(0, 0);
  __syncthreads();

  for (int kc = 0; kc < 4; ++kc) {
    const int cur = kc & 1;
    if (kc < 3) STAGE_KV(kc + 1, cur ^ 1);  // prefetch; drained by end-of-iter sync

    f32x4 sc[4][4] = {};
    __builtin_amdgcn_s_setprio(1);
#pragma unroll
    for (int kk = 0; kk < 2; ++kk) {
      bf16x8 kf[4];
#pragma unroll
      for (int ni = 0; ni < 4; ++ni) {
        int row = ni * 16 + (ln & 15);
        int ch = (kk * 4 + (ln >> 4)) ^ (row & 7);
        kf[ni] = *(const bf16x8*)(&Kl[cur][row * 64 + ch * 8]);
      }
#pragma unroll
      for (int mi = 0; mi < 4; ++mi)
#pragma unroll
        for (int ni = 0; ni < 4; ++ni)
          sc[mi][ni] = __builtin_amdgcn_mfma_f32_16x16x32_bf16(qf[mi][kk], kf[ni], sc[mi][ni], 0, 0, 0);
    }
    __builtin_amdgcn_s_setprio(0);
#pragma unroll
    for (int mi = 0; mi < 4; ++mi)
#pragma unroll
      for (int ni = 0; ni < 4; ++ni) sc[mi][ni] *= 0.125f;

#pragma unroll
    for (int mi = 0; mi < 4; ++mi) {
#pragma unroll
      for (int r = 0; r < 4; ++r) {
        float mx = fmaxf(fmaxf(sc[mi][0][r], sc[mi][1][r]), fmaxf(sc[mi][2][r], sc[mi][3][r]));
#pragma unroll
        for (int d = 1; d < 16; d <<= 1) mx = fmaxf(mx, __shfl_xor(mx, d));
        float mn = fmaxf(mr[mi][r], mx);
        float scal = __expf(mr[mi][r] - mn);
        mr[mi][r] = mn;
        float rs = 0.f;
#pragma unroll
        for (int ni = 0; ni < 4; ++ni) {
          float p = __expf(sc[mi][ni][r] - mn);
          sc[mi][ni][r] = p;
          rs += p;
        }
#pragma unroll
        for (int d = 1; d < 16; d <<= 1) rs += __shfl_xor(rs, d);
        lr[mi][r] = lr[mi][r] * scal + rs;
#pragma unroll
        for (int nd = 0; nd < 4; ++nd) o[mi][nd][r] *= scal;
      }
    }

    bf16_t* P = Pl[wv];
#pragma unroll
    for (int mi = 0; mi < 4; ++mi)
#pragma unroll
      for (int ni = 0; ni < 4; ++ni)
#pragma unroll
        for (int r = 0; r < 4; ++r) {
          int row = mi * 16 + ((ln >> 4) << 2) + r;
          int col = ni * 16 + (ln & 15);
          P[row * 64 + (col ^ ((row & 7) << 3))] = (bf16_t)sc[mi][ni][r];
        }
    __builtin_amdgcn_s_setprio(1);
#pragma unroll
    for (int kk = 0; kk < 2; ++kk) {
      bf16x8 pf[4], vf[4];
#pragma unroll
      for (int mi = 0; mi < 4; ++mi) {
        int row = mi * 16 + (ln & 15);
        int ch = (kk * 4 + (ln >> 4)) ^ (row & 7);
        pf[mi] = *(const bf16x8*)(P + row * 64 + ch * 8);
      }
#pragma unroll
      for (int nd = 0; nd < 4; ++nd) {
        int row = nd * 16 + (ln & 15);
        int ch = (kk * 4 + (ln >> 4)) ^ (row & 7);
        vf[nd] = *(const bf16x8*)(&Vl[cur][row * 64 + ch * 8]);
      }
#pragma unroll
      for (int mi = 0; mi < 4; ++mi)
#pragma unroll
        for (int nd = 0; nd < 4; ++nd)
          o[mi][nd] = __builtin_amdgcn_mfma_f32_16x16x32_bf16(pf[mi], vf[nd], o[mi][nd], 0, 0, 0);
    }
    __builtin_amdgcn_s_setprio(0);
    __syncthreads();  // drains prefetch vmcnt + LDS reuse fence
  }
#undef STAGE_KV

#pragma unroll
  for (int mi = 0; mi < 4; ++mi)
#pragma unroll
    for (int nd = 0; nd < 4; ++nd)
#pragma unroll
      for (int r = 0; r < 4; ++r) {
        int m = qrow0 + mi * 16 + ((ln >> 4) << 2) + r;
        int col = h * DD + nd * 16 + (ln & 15);
        float gv = (float)G[(size_t)m * EE + col];
        float sig = 1.f / (1.f + __expf(-gv));
        AO[(size_t)m * EE + col] = (bf16_t)((o[mi][nd][r] / lr[mi][r]) * sig);
      }
}

extern "C" void kernel_launch(void* const* d_in, const int* in_sizes, int n_in,
                              void* d_out, int out_size, void* d_ws, size_t ws_size,
                              hipStream_t stream) {
  const float* x = (const float*)d_in[0];
  const float* Wq = (const float*)d_in[1];
  const float* Wk = (const float*)d_in[2];
  const float* Wv = (const float*)d_in[3];
  const float* Wg = (const float*)d_in[4];
  const float* Wo = (const float*)d_in[5];
  const float* cosp = (const float*)d_in[6];
  const float* sinp = (const float*)d_in[7];
  float* out = (float*)d_out;

  char* ws = (char*)d_ws;
  bf16_t* XB = (bf16_t*)(ws);                       // 16MB: x bf16; reused as gated AO
  bf16_t* WT = (bf16_t*)(ws + (16ll << 20));        // 10MB: [5][1024][1024] W^T bf16 (q,k,v,g,o)
  bf16_t* QB = (bf16_t*)(ws + (26ll << 20));        // 16MB: Q (roped)
  bf16_t* KB = (bf16_t*)(ws + (42ll << 20));        // 16MB: K (roped)
  bf16_t* VT = (bf16_t*)(ws + (58ll << 20));        // 16MB: V transposed [B][H][D][S]
  bf16_t* GB = (bf16_t*)(ws + (74ll << 20));        // 16MB: gate
  bf16_t* AO = XB;                                  // gated attention output reuses XB region

  const int n8 = MM * EE / 8;  // 1048576
  cvt_kernel<<<n8 / 256, 256, 0, stream>>>(x, XB, n8);
  wt_kernel<<<dim3(32, 32, 5), 256, 0, stream>>>(Wq, Wk, Wv, Wg, Wo, WT);
  // QKVG: grid (64 m-tiles, 32 n-tiles over 4096 cols); RoPE + V^T fused in epilogue
  gemm_bt<0><<<dim3(MM / 128, 4 * EE / 128), 256, 0, stream>>>(XB, WT, QB, cosp, sinp);
  attn_kernel<<<BB * (SS / 256) * HH, 256, 0, stream>>>(QB, KB, VT, GB, AO);
  gemm_bt<1><<<dim3(MM / 128, EE / 128), 256, 0, stream>>>(AO, WT + (size_t)4 * EE * EE, out,
                                                           nullptr, nullptr);
}

// Round 6
// 185.699 us; speedup vs baseline: 1.0274x; 1.0274x over previous
//
#include <hip/hip_runtime.h>
#include <hip/hip_bf16.h>
#include <stdint.h>

typedef __bf16 bf16_t;
typedef __bf16 bf16x8 __attribute__((ext_vector_type(8)));
typedef float f32x4 __attribute__((ext_vector_type(4)));

#define DEVI __device__ __forceinline__

constexpr int BB = 2;       // batch
constexpr int SS = 4096;    // seq
constexpr int EE = 1024;    // embed
constexpr int HH = 16;      // heads
constexpr int DD = 64;      // head dim
constexpr int MM = BB * SS; // 8192 token rows

// async global->LDS, 16B per lane; LDS dest must be wave-uniform base (HW adds lane*16)
DEVI void gload16(const void* g, void* l) {
  __builtin_amdgcn_global_load_lds(
      (const __attribute__((address_space(1))) void*)g,
      (__attribute__((address_space(3))) void*)l, 16, 0, 0);
}

// ---------------- f32 -> bf16 convert (vectorized 8/thread) ----------------
__global__ void cvt_kernel(const float* __restrict__ in, bf16_t* __restrict__ out, int n8) {
  int i = blockIdx.x * 256 + threadIdx.x;
  if (i >= n8) return;
  const float* p = in + (size_t)i * 8;
  bf16x8 o;
#pragma unroll
  for (int j = 0; j < 8; ++j) o[j] = (bf16_t)p[j];
  *(bf16x8*)(out + (size_t)i * 8) = o;
}

// ---------------- weight transpose + cvt: W[k][n] f32 -> WT[n][k] bf16 ----------------
__global__ void wt_kernel(const float* __restrict__ w0, const float* __restrict__ w1,
                          const float* __restrict__ w2, const float* __restrict__ w3,
                          const float* __restrict__ w4, bf16_t* __restrict__ out) {
  __shared__ float tile[32][33];
  const float* Wsel = blockIdx.z == 0 ? w0 : blockIdx.z == 1 ? w1 :
                      blockIdx.z == 2 ? w2 : blockIdx.z == 3 ? w3 : w4;
  bf16_t* O = out + (size_t)blockIdx.z * EE * EE;
  int n0 = blockIdx.x * 32, k0 = blockIdx.y * 32;
  int tx = threadIdx.x & 31, ty = threadIdx.x >> 5;
#pragma unroll
  for (int i = 0; i < 4; ++i)
    tile[ty + i * 8][tx] = Wsel[(size_t)(k0 + ty + i * 8) * EE + n0 + tx];
  __syncthreads();
#pragma unroll
  for (int i = 0; i < 4; ++i)
    O[(size_t)(n0 + ty + i * 8) * EE + k0 + tx] = (bf16_t)tile[tx][ty + i * 8];
}

// ---------------- GEMM: C[M][N] = A[M][K] @ Bt[N][K]^T, 128x128 tile, BK=64 ----------------
// m97-style 2-barrier structure (proven 825 TF on this shape).
// MODE 0: QKVG — bf16 out into 4 contiguous regions; widx uniform per block (n0>>10).
//         widx==2 (V): transposed [B][H][D][S]. Q/K/G: plain rows (RoPE applied later in attn).
// MODE 1: f32 out [M][1024] (final projection).
template <int MODE>
__global__ __launch_bounds__(256) void gemm_bt(const bf16_t* __restrict__ A,
                                               const bf16_t* __restrict__ Bt,
                                               void* __restrict__ Cout) {
  __shared__ bf16_t Al[128 * 64];
  __shared__ bf16_t Bl[128 * 64];
  const int m0 = blockIdx.x * 128;
  const int n0 = blockIdx.y * 128;
  const int tid = threadIdx.x;
  const int wv = tid >> 6, ln = tid & 63;
  const int wm = wv >> 1, wn = wv & 1;
  f32x4 acc[4][4] = {};

  for (int k0 = 0; k0 < EE; k0 += 64) {
    __syncthreads();  // prior iter's LDS readers done before overwrite
#pragma unroll
    for (int i = 0; i < 4; ++i) {
      int slot = i * 256 + wv * 64 + ln;  // 16B slots, 8 per 128B row
      int r = slot >> 3, c = slot & 7;
      int cs = c ^ (r & 7);  // inverse-swizzled source chunk (linear LDS dest)
      gload16(A + (size_t)(m0 + r) * EE + k0 + cs * 8, Al + (size_t)(i * 256 + wv * 64) * 8);
      gload16(Bt + (size_t)(n0 + r) * EE + k0 + cs * 8, Bl + (size_t)(i * 256 + wv * 64) * 8);
    }
    __syncthreads();  // compiler drains vmcnt(0) before barrier
#pragma unroll
    for (int kk = 0; kk < 2; ++kk) {
      bf16x8 af[4], bfr[4];
#pragma unroll
      for (int mi = 0; mi < 4; ++mi) {
        int row = wm * 64 + mi * 16 + (ln & 15);
        int ch = (kk * 4 + (ln >> 4)) ^ (row & 7);
        af[mi] = *(const bf16x8*)(Al + row * 64 + ch * 8);
      }
#pragma unroll
      for (int ni = 0; ni < 4; ++ni) {
        int row = wn * 64 + ni * 16 + (ln & 15);
        int ch = (kk * 4 + (ln >> 4)) ^ (row & 7);
        bfr[ni] = *(const bf16x8*)(Bl + row * 64 + ch * 8);
      }
#pragma unroll
      for (int mi = 0; mi < 4; ++mi)
#pragma unroll
        for (int ni = 0; ni < 4; ++ni)
          acc[mi][ni] = __builtin_amdgcn_mfma_f32_16x16x32_bf16(af[mi], bfr[ni], acc[mi][ni], 0, 0, 0);
    }
  }

  if (MODE == 0) {
    const int widx = n0 >> 10;
    const int cb = (n0 & 1023) + wn * 64;  // region-local col base (head-aligned)
    bf16_t* W = (bf16_t*)Cout + (size_t)widx * MM * EE;
    if (widx == 2) {  // V: write transposed [B][H][D][S]
#pragma unroll
      for (int mi = 0; mi < 4; ++mi)
#pragma unroll
        for (int ni = 0; ni < 4; ++ni) {
          int row = m0 + wm * 64 + mi * 16 + ((ln >> 4) << 2);
          int ncol = cb + ni * 16 + (ln & 15);
          int h = ncol >> 6, d = ncol & 63;
          int b = row >> 12, s = row & (SS - 1);
          bf16_t* p = W + (((size_t)b * HH + h) * DD + d) * SS + s;
#pragma unroll
          for (int r = 0; r < 4; ++r) p[r] = (bf16_t)acc[mi][ni][r];
        }
    } else {  // Q, K, G: plain row-major
#pragma unroll
      for (int mi = 0; mi < 4; ++mi)
#pragma unroll
        for (int ni = 0; ni < 4; ++ni) {
          int row = m0 + wm * 64 + mi * 16 + ((ln >> 4) << 2);
          bf16_t* p = W + (size_t)row * EE + cb + ni * 16 + (ln & 15);
#pragma unroll
          for (int r = 0; r < 4; ++r) p[(size_t)r * EE] = (bf16_t)acc[mi][ni][r];
        }
    }
  } else {
    float* O = (float*)Cout;
#pragma unroll
    for (int mi = 0; mi < 4; ++mi)
#pragma unroll
      for (int ni = 0; ni < 4; ++ni) {
        int row = m0 + wm * 64 + mi * 16 + ((ln >> 4) << 2);
        int col = n0 + wn * 64 + ni * 16 + (ln & 15);
#pragma unroll
        for (int r = 0; r < 4; ++r) O[(size_t)(row + r) * EE + col] = acc[mi][ni][r];
      }
  }
}

// ---------------- block-diagonal attention + fused RoPE + fused sigmoid gate ----------------
// grid: B*nb*H = 512 blocks; 8 waves x 32 q-rows. K/V double-buffered (1 gload16/thread).
// Q roped in-register at load; K roped in-LDS once per staged tile.
__global__ __launch_bounds__(512, 4) void attn_kernel(const bf16_t* __restrict__ Q,
                                                      const bf16_t* __restrict__ Kc,
                                                      const bf16_t* __restrict__ Vt,
                                                      const bf16_t* __restrict__ G,
                                                      const float* __restrict__ cosp,
                                                      const float* __restrict__ sinp,
                                                      bf16_t* __restrict__ AO) {
  __shared__ bf16_t Kl[2][64 * 64];
  __shared__ bf16_t Vl[2][64 * 64];
  __shared__ bf16_t Pl[8][32 * 64];
  const int bx = blockIdx.x;
  const int h = bx & 15, sb = (bx >> 4) & 15, b = bx >> 8;
  const int tid = threadIdx.x, wv = tid >> 6, ln = tid & 63;
  const int qs0 = sb * 256 + wv * 32;  // seq base for this wave's 32 q-rows

  // ---- Q fragments + in-register RoPE (s is per-lane; d-octet d0 = (ln>>4)*8)
  bf16x8 qf[2][2];
  const int d0 = (ln >> 4) << 3;
#pragma unroll
  for (int mi = 0; mi < 2; ++mi) {
    int qs = qs0 + mi * 16 + (ln & 15);
    const bf16_t* qp = Q + ((size_t)b * SS + qs) * EE + h * DD;
    qf[mi][0] = *(const bf16x8*)(qp + d0);
    qf[mi][1] = *(const bf16x8*)(qp + 32 + d0);
    float cl[8], sl[8], chv[8], shv[8];
    *(f32x4*)&cl[0] = *(const f32x4*)&cosp[qs * DD + d0];
    *(f32x4*)&cl[4] = *(const f32x4*)&cosp[qs * DD + d0 + 4];
    *(f32x4*)&chv[0] = *(const f32x4*)&cosp[qs * DD + d0 + 32];
    *(f32x4*)&chv[4] = *(const f32x4*)&cosp[qs * DD + d0 + 36];
    *(f32x4*)&sl[0] = *(const f32x4*)&sinp[qs * DD + d0];
    *(f32x4*)&sl[4] = *(const f32x4*)&sinp[qs * DD + d0 + 4];
    *(f32x4*)&shv[0] = *(const f32x4*)&sinp[qs * DD + d0 + 32];
    *(f32x4*)&shv[4] = *(const f32x4*)&sinp[qs * DD + d0 + 36];
#pragma unroll
    for (int j = 0; j < 8; ++j) {
      float lo = (float)qf[mi][0][j], hi = (float)qf[mi][1][j];
      qf[mi][0][j] = (bf16_t)(lo * cl[j] - hi * sl[j]);
      qf[mi][1][j] = (bf16_t)(hi * chv[j] + lo * shv[j]);
    }
  }

  f32x4 o[2][4] = {};
  float mr[2][4], lr[2][4];
#pragma unroll
  for (int i = 0; i < 2; ++i)
#pragma unroll
    for (int r = 0; r < 4; ++r) { mr[i][r] = -1e30f; lr[i][r] = 0.f; }

  // staging: 512 threads, 1 gload each for K and V; dest = wave-uniform base + lane*16
#define STAGE_KV(KC, BI) do {                                                        \
    int r_ = tid >> 3, c_ = tid & 7, cs_ = c_ ^ (r_ & 7);                            \
    gload16(Kc + ((size_t)b * SS + sb * 256 + (KC) * 64 + r_) * EE + h * DD + cs_ * 8, \
            &Kl[BI][wv * 512]);                                                      \
    gload16(Vt + (((size_t)b * HH + h) * DD + r_) * SS + sb * 256 + (KC) * 64 + cs_ * 8, \
            &Vl[BI][wv * 512]);                                                      \
  } while (0)

  STAGE_KV(0, 0);
  __syncthreads();

  for (int kc = 0; kc < 4; ++kc) {
    const int cur = kc & 1;
    if (kc < 3) STAGE_KV(kc + 1, cur ^ 1);  // async prefetch; drained by end-of-iter sync

    // ---- K-rope in LDS: 256 threads, each handles one (row, d-octet) pair d <-> d+32
    if (tid < 256) {
      int r_ = tid >> 2, c_ = tid & 3;
      int ks = sb * 256 + kc * 64 + r_;
      int chl = ((c_ ^ (r_ & 7)) << 3), chh = (((c_ ^ 4) ^ (r_ & 7)) << 3);
      bf16x8 lo8 = *(bf16x8*)&Kl[cur][r_ * 64 + chl];
      bf16x8 hi8 = *(bf16x8*)&Kl[cur][r_ * 64 + chh];
      float cl[8], sl[8], chv[8], shv[8];
      *(f32x4*)&cl[0] = *(const f32x4*)&cosp[ks * DD + c_ * 8];
      *(f32x4*)&cl[4] = *(const f32x4*)&cosp[ks * DD + c_ * 8 + 4];
      *(f32x4*)&chv[0] = *(const f32x4*)&cosp[ks * DD + c_ * 8 + 32];
      *(f32x4*)&chv[4] = *(const f32x4*)&cosp[ks * DD + c_ * 8 + 36];
      *(f32x4*)&sl[0] = *(const f32x4*)&sinp[ks * DD + c_ * 8];
      *(f32x4*)&sl[4] = *(const f32x4*)&sinp[ks * DD + c_ * 8 + 4];
      *(f32x4*)&shv[0] = *(const f32x4*)&sinp[ks * DD + c_ * 8 + 32];
      *(f32x4*)&shv[4] = *(const f32x4*)&sinp[ks * DD + c_ * 8 + 36];
      bf16x8 olo, ohi;
#pragma unroll
      for (int j = 0; j < 8; ++j) {
        float lo = (float)lo8[j], hi = (float)hi8[j];
        olo[j] = (bf16_t)(lo * cl[j] - hi * sl[j]);
        ohi[j] = (bf16_t)(hi * chv[j] + lo * shv[j]);
      }
      *(bf16x8*)&Kl[cur][r_ * 64 + chl] = olo;
      *(bf16x8*)&Kl[cur][r_ * 64 + chh] = ohi;
    }
    __syncthreads();  // roped K visible to all waves

    // ---- QK^T: S[32q][64k] per wave
    f32x4 sc[2][4] = {};
    __builtin_amdgcn_s_setprio(1);
#pragma unroll
    for (int kk = 0; kk < 2; ++kk) {
      bf16x8 kf[4];
#pragma unroll
      for (int ni = 0; ni < 4; ++ni) {
        int row = ni * 16 + (ln & 15);
        int ch = (kk * 4 + (ln >> 4)) ^ (row & 7);
        kf[ni] = *(const bf16x8*)(&Kl[cur][row * 64 + ch * 8]);
      }
#pragma unroll
      for (int mi = 0; mi < 2; ++mi)
#pragma unroll
        for (int ni = 0; ni < 4; ++ni)
          sc[mi][ni] = __builtin_amdgcn_mfma_f32_16x16x32_bf16(qf[mi][kk], kf[ni], sc[mi][ni], 0, 0, 0);
    }
    __builtin_amdgcn_s_setprio(0);
#pragma unroll
    for (int mi = 0; mi < 2; ++mi)
#pragma unroll
      for (int ni = 0; ni < 4; ++ni) sc[mi][ni] *= 0.125f;  // 1/sqrt(64)

    // ---- online softmax (rows: (ln>>4)*4 + r per mi-tile; cols spread over ln&15, ni)
#pragma unroll
    for (int mi = 0; mi < 2; ++mi) {
#pragma unroll
      for (int r = 0; r < 4; ++r) {
        float mx = fmaxf(fmaxf(sc[mi][0][r], sc[mi][1][r]), fmaxf(sc[mi][2][r], sc[mi][3][r]));
#pragma unroll
        for (int d = 1; d < 16; d <<= 1) mx = fmaxf(mx, __shfl_xor(mx, d));
        float mn = fmaxf(mr[mi][r], mx);
        float scal = __expf(mr[mi][r] - mn);
        mr[mi][r] = mn;
        float rs = 0.f;
#pragma unroll
        for (int ni = 0; ni < 4; ++ni) {
          float p = __expf(sc[mi][ni][r] - mn);
          sc[mi][ni][r] = p;
          rs += p;
        }
#pragma unroll
        for (int d = 1; d < 16; d <<= 1) rs += __shfl_xor(rs, d);
        lr[mi][r] = lr[mi][r] * scal + rs;
#pragma unroll
        for (int nd = 0; nd < 4; ++nd) o[mi][nd][r] *= scal;
      }
    }

    // ---- P -> per-wave LDS (swizzled), then PV
    bf16_t* P = Pl[wv];
#pragma unroll
    for (int mi = 0; mi < 2; ++mi)
#pragma unroll
      for (int ni = 0; ni < 4; ++ni)
#pragma unroll
        for (int r = 0; r < 4; ++r) {
          int row = mi * 16 + ((ln >> 4) << 2) + r;
          int col = ni * 16 + (ln & 15);
          P[row * 64 + (col ^ ((row & 7) << 3))] = (bf16_t)sc[mi][ni][r];
        }
    __builtin_amdgcn_s_setprio(1);
#pragma unroll
    for (int kk = 0; kk < 2; ++kk) {
      bf16x8 pf[2], vf[4];
#pragma unroll
      for (int mi = 0; mi < 2; ++mi) {
        int row = mi * 16 + (ln & 15);
        int ch = (kk * 4 + (ln >> 4)) ^ (row & 7);
        pf[mi] = *(const bf16x8*)(P + row * 64 + ch * 8);
      }
#pragma unroll
      for (int nd = 0; nd < 4; ++nd) {
        int row = nd * 16 + (ln & 15);
        int ch = (kk * 4 + (ln >> 4)) ^ (row & 7);
        vf[nd] = *(const bf16x8*)(&Vl[cur][row * 64 + ch * 8]);
      }
#pragma unroll
      for (int mi = 0; mi < 2; ++mi)
#pragma unroll
        for (int nd = 0; nd < 4; ++nd)
          o[mi][nd] = __builtin_amdgcn_mfma_f32_16x16x32_bf16(pf[mi], vf[nd], o[mi][nd], 0, 0, 0);
    }
    __builtin_amdgcn_s_setprio(0);
    __syncthreads();  // drains prefetch vmcnt + LDS reuse fence
  }
#undef STAGE_KV

  // ---- epilogue: normalize, sigmoid-gate, store
#pragma unroll
  for (int mi = 0; mi < 2; ++mi)
#pragma unroll
    for (int r = 0; r < 4; ++r) {
      float inv = 1.f / lr[mi][r];
      int m = (int)((size_t)b * SS) + qs0 + mi * 16 + ((ln >> 4) << 2) + r;
#pragma unroll
      for (int nd = 0; nd < 4; ++nd) {
        int col = h * DD + nd * 16 + (ln & 15);
        float gv = (float)G[(size_t)m * EE + col];
        float sig = 1.f / (1.f + __expf(-gv));
        AO[(size_t)m * EE + col] = (bf16_t)((o[mi][nd][r] * inv) * sig);
      }
    }
}

extern "C" void kernel_launch(void* const* d_in, const int* in_sizes, int n_in,
                              void* d_out, int out_size, void* d_ws, size_t ws_size,
                              hipStream_t stream) {
  const float* x = (const float*)d_in[0];
  const float* Wq = (const float*)d_in[1];
  const float* Wk = (const float*)d_in[2];
  const float* Wv = (const float*)d_in[3];
  const float* Wg = (const float*)d_in[4];
  const float* Wo = (const float*)d_in[5];
  const float* cosp = (const float*)d_in[6];
  const float* sinp = (const float*)d_in[7];
  float* out = (float*)d_out;

  char* ws = (char*)d_ws;
  bf16_t* XB = (bf16_t*)(ws);                       // 16MB: x bf16; reused as gated AO
  bf16_t* WT = (bf16_t*)(ws + (16ll << 20));        // 10MB: [5][1024][1024] W^T bf16 (q,k,v,g,o)
  bf16_t* QB = (bf16_t*)(ws + (26ll << 20));        // 16MB: Q (unroped)
  bf16_t* KB = (bf16_t*)(ws + (42ll << 20));        // 16MB: K (unroped)
  bf16_t* VT = (bf16_t*)(ws + (58ll << 20));        // 16MB: V transposed [B][H][D][S]
  bf16_t* GB = (bf16_t*)(ws + (74ll << 20));        // 16MB: gate
  bf16_t* AO = XB;                                  // gated attention output reuses XB region

  const int n8 = MM * EE / 8;  // 1048576
  cvt_kernel<<<n8 / 256, 256, 0, stream>>>(x, XB, n8);
  wt_kernel<<<dim3(32, 32, 5), 256, 0, stream>>>(Wq, Wk, Wv, Wg, Wo, WT);
  gemm_bt<0><<<dim3(MM / 128, 4 * EE / 128), 256, 0, stream>>>(XB, WT, QB);
  attn_kernel<<<BB * (SS / 256) * HH, 512, 0, stream>>>(QB, KB, VT, GB, cosp, sinp, AO);
  gemm_bt<1><<<dim3(MM / 128, EE / 128), 256, 0, stream>>>(AO, WT + (size_t)4 * EE * EE, out);
}

// Round 7
// 163.824 us; speedup vs baseline: 1.1646x; 1.1335x over previous
//
#include <hip/hip_runtime.h>
#include <hip/hip_bf16.h>
#include <stdint.h>

typedef __bf16 bf16_t;
typedef __bf16 bf16x8 __attribute__((ext_vector_type(8)));
typedef float f32x4 __attribute__((ext_vector_type(4)));

#define DEVI __device__ __forceinline__

constexpr int BB = 2;       // batch
constexpr int SS = 4096;    // seq
constexpr int EE = 1024;    // embed
constexpr int HH = 16;      // heads
constexpr int DD = 64;      // head dim
constexpr int MM = BB * SS; // 8192 token rows

// async global->LDS, 16B per lane; LDS dest must be wave-uniform base (HW adds lane*16)
DEVI void gload16(const void* g, void* l) {
  __builtin_amdgcn_global_load_lds(
      (const __attribute__((address_space(1))) void*)g,
      (__attribute__((address_space(3))) void*)l, 16, 0, 0);
}

// ---------------- f32 -> bf16 convert (vectorized 8/thread) ----------------
__global__ void cvt_kernel(const float* __restrict__ in, bf16_t* __restrict__ out, int n8) {
  int i = blockIdx.x * 256 + threadIdx.x;
  if (i >= n8) return;
  const float* p = in + (size_t)i * 8;
  bf16x8 o;
#pragma unroll
  for (int j = 0; j < 8; ++j) o[j] = (bf16_t)p[j];
  *(bf16x8*)(out + (size_t)i * 8) = o;
}

// ---------------- weight transpose + cvt: W[k][n] f32 -> WT[n][k] bf16 ----------------
__global__ void wt_kernel(const float* __restrict__ w0, const float* __restrict__ w1,
                          const float* __restrict__ w2, const float* __restrict__ w3,
                          const float* __restrict__ w4, bf16_t* __restrict__ out) {
  __shared__ float tile[32][33];
  const float* Wsel = blockIdx.z == 0 ? w0 : blockIdx.z == 1 ? w1 :
                      blockIdx.z == 2 ? w2 : blockIdx.z == 3 ? w3 : w4;
  bf16_t* O = out + (size_t)blockIdx.z * EE * EE;
  int n0 = blockIdx.x * 32, k0 = blockIdx.y * 32;
  int tx = threadIdx.x & 31, ty = threadIdx.x >> 5;
#pragma unroll
  for (int i = 0; i < 4; ++i)
    tile[ty + i * 8][tx] = Wsel[(size_t)(k0 + ty + i * 8) * EE + n0 + tx];
  __syncthreads();
#pragma unroll
  for (int i = 0; i < 4; ++i)
    O[(size_t)(n0 + ty + i * 8) * EE + k0 + tx] = (bf16_t)tile[tx][ty + i * 8];
}

// ---------------- GEMM: C[M][N] = A[M][K] @ Bt[N][K]^T, 128x128 tile, BK=64 ----------------
// m97-style 2-barrier structure. #pragma unroll 1 on the K-loop is REQUIRED: full unroll
// (trip=16 known) bloats the body 16x, VGPR 80->88, occupancy 27->20% (r6 regression).
// MODE 0: QKVG bf16 out, 4 contiguous regions; widx==2 (V) transposed [B][H][D][S].
// MODE 1: f32 out (final projection).
template <int MODE>
__global__ __launch_bounds__(256) void gemm_bt(const bf16_t* __restrict__ A,
                                               const bf16_t* __restrict__ Bt,
                                               void* __restrict__ Cout) {
  __shared__ bf16_t Al[128 * 64];
  __shared__ bf16_t Bl[128 * 64];
  const int m0 = blockIdx.x * 128;
  const int n0 = blockIdx.y * 128;
  const int tid = threadIdx.x;
  const int wv = tid >> 6, ln = tid & 63;
  const int wm = wv >> 1, wn = wv & 1;
  f32x4 acc[4][4] = {};

#pragma unroll 1
  for (int k0 = 0; k0 < EE; k0 += 64) {
    __syncthreads();  // prior iter's LDS readers done before overwrite
#pragma unroll
    for (int i = 0; i < 4; ++i) {
      int slot = i * 256 + wv * 64 + ln;  // 16B slots, 8 per 128B row
      int r = slot >> 3, c = slot & 7;
      int cs = c ^ (r & 7);  // inverse-swizzled source chunk (linear LDS dest)
      gload16(A + (size_t)(m0 + r) * EE + k0 + cs * 8, Al + (size_t)(i * 256 + wv * 64) * 8);
      gload16(Bt + (size_t)(n0 + r) * EE + k0 + cs * 8, Bl + (size_t)(i * 256 + wv * 64) * 8);
    }
    __syncthreads();  // compiler drains vmcnt(0) before barrier
#pragma unroll
    for (int kk = 0; kk < 2; ++kk) {
      bf16x8 af[4], bfr[4];
#pragma unroll
      for (int mi = 0; mi < 4; ++mi) {
        int row = wm * 64 + mi * 16 + (ln & 15);
        int ch = (kk * 4 + (ln >> 4)) ^ (row & 7);
        af[mi] = *(const bf16x8*)(Al + row * 64 + ch * 8);
      }
#pragma unroll
      for (int ni = 0; ni < 4; ++ni) {
        int row = wn * 64 + ni * 16 + (ln & 15);
        int ch = (kk * 4 + (ln >> 4)) ^ (row & 7);
        bfr[ni] = *(const bf16x8*)(Bl + row * 64 + ch * 8);
      }
#pragma unroll
      for (int mi = 0; mi < 4; ++mi)
#pragma unroll
        for (int ni = 0; ni < 4; ++ni)
          acc[mi][ni] = __builtin_amdgcn_mfma_f32_16x16x32_bf16(af[mi], bfr[ni], acc[mi][ni], 0, 0, 0);
    }
  }

  if (MODE == 0) {
    const int widx = n0 >> 10;
    const int cb = (n0 & 1023) + wn * 64;  // region-local col base (head-aligned)
    bf16_t* W = (bf16_t*)Cout + (size_t)widx * MM * EE;
    if (widx == 2) {  // V: write transposed [B][H][D][S]
#pragma unroll
      for (int mi = 0; mi < 4; ++mi)
#pragma unroll
        for (int ni = 0; ni < 4; ++ni) {
          int row = m0 + wm * 64 + mi * 16 + ((ln >> 4) << 2);
          int ncol = cb + ni * 16 + (ln & 15);
          int h = ncol >> 6, d = ncol & 63;
          int b = row >> 12, s = row & (SS - 1);
          bf16_t* p = W + (((size_t)b * HH + h) * DD + d) * SS + s;
#pragma unroll
          for (int r = 0; r < 4; ++r) p[r] = (bf16_t)acc[mi][ni][r];
        }
    } else {  // Q, K, G: plain row-major
#pragma unroll
      for (int mi = 0; mi < 4; ++mi)
#pragma unroll
        for (int ni = 0; ni < 4; ++ni) {
          int row = m0 + wm * 64 + mi * 16 + ((ln >> 4) << 2);
          bf16_t* p = W + (size_t)row * EE + cb + ni * 16 + (ln & 15);
#pragma unroll
          for (int r = 0; r < 4; ++r) p[(size_t)r * EE] = (bf16_t)acc[mi][ni][r];
        }
    }
  } else {
    float* O = (float*)Cout;
#pragma unroll
    for (int mi = 0; mi < 4; ++mi)
#pragma unroll
      for (int ni = 0; ni < 4; ++ni) {
        int row = m0 + wm * 64 + mi * 16 + ((ln >> 4) << 2);
        int col = n0 + wn * 64 + ni * 16 + (ln & 15);
#pragma unroll
        for (int r = 0; r < 4; ++r) O[(size_t)(row + r) * EE + col] = acc[mi][ni][r];
      }
  }
}

// ---------------- block-diagonal attention + fused RoPE + fused sigmoid gate ----------------
// grid: 1024 half-blocks (2 per (b,sb,h)); 4 waves x 32 q-rows; 2 blocks/CU co-resident.
// Full 256-key staging: K (roped in LDS once) + V^T staged up front, exact softmax
// (no online rescale), PV via per-wave P-LDS chunks. Only 2 barriers per block.
__global__ __launch_bounds__(256, 2) void attn_kernel(const bf16_t* __restrict__ Q,
                                                      const bf16_t* __restrict__ Kc,
                                                      const bf16_t* __restrict__ Vt,
                                                      const bf16_t* __restrict__ G,
                                                      const float* __restrict__ cosp,
                                                      const float* __restrict__ sinp,
                                                      bf16_t* __restrict__ AO) {
  __shared__ bf16_t Kl[256 * 64];   // 32KB: K rows (roped), row-swizzled chunks
  __shared__ bf16_t Vl[64 * 256];   // 32KB: V^T [d][s], chunk-swizzle c^((d&7)<<2)
  __shared__ bf16_t Pl[4][32 * 64]; // 16KB: per-wave P chunk
  const int id = blockIdx.x;
  const int swz = (id & 7) * 128 + (id >> 3);  // XCD swizzle: half-block pairs share an XCD
  const int half = swz & 1, ab = swz >> 1;
  const int h = ab & 15, sb = (ab >> 4) & 15, b = ab >> 8;
  const int tid = threadIdx.x, wv = tid >> 6, ln = tid & 63;
  const int qs0 = sb * 256 + half * 128 + wv * 32;  // this wave's 32 q-rows (seq index)

  // ---- stage full K (8 groups) + full V^T (8 groups): 16 gload16/thread
  {
    const bf16_t* Kbase = Kc + ((size_t)b * SS + sb * 256) * EE + h * DD;
    int kr = wv * 8 + (ln >> 3), kc8 = ln & 7;
#pragma unroll
    for (int g = 0; g < 8; ++g) {
      int r = g * 32 + kr, cs = kc8 ^ (r & 7);
      gload16(Kbase + (size_t)r * EE + cs * 8, &Kl[g * 2048 + wv * 512]);
    }
    const bf16_t* Vbase = Vt + ((size_t)b * HH + h) * DD * SS + sb * 256;
    int vr = wv * 2 + (ln >> 5), vc = ln & 31;
#pragma unroll
    for (int g = 0; g < 8; ++g) {
      int r = g * 8 + vr, cs = vc ^ ((r & 7) << 2);
      gload16(Vbase + (size_t)r * SS + cs * 8, &Vl[g * 2048 + wv * 512]);
    }
  }
  __syncthreads();  // drains all gloads

  // ---- K-rope in LDS: 256 threads x 4 rows each; octet pair d <-> d+32
  {
    int c_ = tid & 3;
#pragma unroll
    for (int rr = 0; rr < 4; ++rr) {
      int r_ = rr * 64 + (tid >> 2);
      int ks = sb * 256 + r_;
      int chl = ((c_ ^ (r_ & 7)) << 3), chh = (((c_ ^ 4) ^ (r_ & 7)) << 3);
      bf16x8 lo8 = *(bf16x8*)&Kl[r_ * 64 + chl];
      bf16x8 hi8 = *(bf16x8*)&Kl[r_ * 64 + chh];
      float cl[8], sl[8], chv[8], shv[8];
      *(f32x4*)&cl[0] = *(const f32x4*)&cosp[ks * DD + c_ * 8];
      *(f32x4*)&cl[4] = *(const f32x4*)&cosp[ks * DD + c_ * 8 + 4];
      *(f32x4*)&chv[0] = *(const f32x4*)&cosp[ks * DD + c_ * 8 + 32];
      *(f32x4*)&chv[4] = *(const f32x4*)&cosp[ks * DD + c_ * 8 + 36];
      *(f32x4*)&sl[0] = *(const f32x4*)&sinp[ks * DD + c_ * 8];
      *(f32x4*)&sl[4] = *(const f32x4*)&sinp[ks * DD + c_ * 8 + 4];
      *(f32x4*)&shv[0] = *(const f32x4*)&sinp[ks * DD + c_ * 8 + 32];
      *(f32x4*)&shv[4] = *(const f32x4*)&sinp[ks * DD + c_ * 8 + 36];
      bf16x8 olo, ohi;
#pragma unroll
      for (int j = 0; j < 8; ++j) {
        float lo = (float)lo8[j], hi = (float)hi8[j];
        olo[j] = (bf16_t)(lo * cl[j] - hi * sl[j]);
        ohi[j] = (bf16_t)(hi * chv[j] + lo * shv[j]);
      }
      *(bf16x8*)&Kl[r_ * 64 + chl] = olo;
      *(bf16x8*)&Kl[r_ * 64 + chh] = ohi;
    }
  }

  // ---- Q fragments + in-register RoPE (overlaps rope/barrier latency)
  bf16x8 qf[2][2];
  const int d0 = (ln >> 4) << 3;
#pragma unroll
  for (int mi = 0; mi < 2; ++mi) {
    int qs = qs0 + mi * 16 + (ln & 15);
    const bf16_t* qp = Q + ((size_t)b * SS + qs) * EE + h * DD;
    qf[mi][0] = *(const bf16x8*)(qp + d0);
    qf[mi][1] = *(const bf16x8*)(qp + 32 + d0);
    float cl[8], sl[8], chv[8], shv[8];
    *(f32x4*)&cl[0] = *(const f32x4*)&cosp[qs * DD + d0];
    *(f32x4*)&cl[4] = *(const f32x4*)&cosp[qs * DD + d0 + 4];
    *(f32x4*)&chv[0] = *(const f32x4*)&cosp[qs * DD + d0 + 32];
    *(f32x4*)&chv[4] = *(const f32x4*)&cosp[qs * DD + d0 + 36];
    *(f32x4*)&sl[0] = *(const f32x4*)&sinp[qs * DD + d0];
    *(f32x4*)&sl[4] = *(const f32x4*)&sinp[qs * DD + d0 + 4];
    *(f32x4*)&shv[0] = *(const f32x4*)&sinp[qs * DD + d0 + 32];
    *(f32x4*)&shv[4] = *(const f32x4*)&sinp[qs * DD + d0 + 36];
#pragma unroll
    for (int j = 0; j < 8; ++j) {
      float lo = (float)qf[mi][0][j], hi = (float)qf[mi][1][j];
      qf[mi][0][j] = (bf16_t)(lo * cl[j] - hi * sl[j]);
      qf[mi][1][j] = (bf16_t)(hi * chv[j] + lo * shv[j]);
    }
  }
  __syncthreads();  // roped K visible to all waves

  // ---- QK^T: full S[32q][256k] in registers (sc[2][16] f32x4 = 128 VGPR)
  f32x4 sc[2][16];
#pragma unroll
  for (int mi = 0; mi < 2; ++mi)
#pragma unroll
    for (int ni = 0; ni < 16; ++ni) sc[mi][ni] = f32x4{0.f, 0.f, 0.f, 0.f};
  __builtin_amdgcn_s_setprio(1);
#pragma unroll
  for (int kk = 0; kk < 2; ++kk) {
#pragma unroll
    for (int ni = 0; ni < 16; ++ni) {
      int row = ni * 16 + (ln & 15);
      int ch = (kk * 4 + (ln >> 4)) ^ (row & 7);
      bf16x8 kf = *(const bf16x8*)(&Kl[row * 64 + ch * 8]);
#pragma unroll
      for (int mi = 0; mi < 2; ++mi)
        sc[mi][ni] = __builtin_amdgcn_mfma_f32_16x16x32_bf16(qf[mi][kk], kf, sc[mi][ni], 0, 0, 0);
    }
  }
  __builtin_amdgcn_s_setprio(0);

  // ---- exact softmax (one pass; reduce in-lane 16, then across ln&15 lanes)
  float lr[2][4];
#pragma unroll
  for (int mi = 0; mi < 2; ++mi) {
#pragma unroll
    for (int r = 0; r < 4; ++r) {
      float mx = -1e30f;
#pragma unroll
      for (int ni = 0; ni < 16; ++ni) mx = fmaxf(mx, sc[mi][ni][r] * 0.125f);
#pragma unroll
      for (int d = 1; d < 16; d <<= 1) mx = fmaxf(mx, __shfl_xor(mx, d));
      float rs = 0.f;
#pragma unroll
      for (int ni = 0; ni < 16; ++ni) {
        float p = __expf(sc[mi][ni][r] * 0.125f - mx);
        sc[mi][ni][r] = p;
        rs += p;
      }
#pragma unroll
      for (int d = 1; d < 16; d <<= 1) rs += __shfl_xor(rs, d);
      lr[mi][r] = rs;
    }
  }

  // ---- PV: per 64-k chunk through per-wave P-LDS (no barriers; per-wave RAW via lgkm)
  f32x4 o[2][4] = {};
  bf16_t* P = Pl[wv];
#pragma unroll
  for (int kc = 0; kc < 4; ++kc) {
#pragma unroll
    for (int mi = 0; mi < 2; ++mi)
#pragma unroll
      for (int nq = 0; nq < 4; ++nq)
#pragma unroll
        for (int r = 0; r < 4; ++r) {
          int row = mi * 16 + ((ln >> 4) << 2) + r;
          int col = nq * 16 + (ln & 15);
          P[row * 64 + (col ^ ((row & 7) << 3))] = (bf16_t)sc[mi][kc * 4 + nq][r];
        }
    __builtin_amdgcn_s_setprio(1);
#pragma unroll
    for (int kk = 0; kk < 2; ++kk) {
      bf16x8 pf[2], vf[4];
#pragma unroll
      for (int mi = 0; mi < 2; ++mi) {
        int row = mi * 16 + (ln & 15);
        int ch = (kk * 4 + (ln >> 4)) ^ (row & 7);
        pf[mi] = *(const bf16x8*)(P + row * 64 + ch * 8);
      }
#pragma unroll
      for (int nd = 0; nd < 4; ++nd) {
        int d = nd * 16 + (ln & 15);
        int c = (kc * 8 + kk * 4 + (ln >> 4)) ^ ((d & 7) << 2);
        vf[nd] = *(const bf16x8*)(&Vl[d * 256 + c * 8]);
      }
#pragma unroll
      for (int mi = 0; mi < 2; ++mi)
#pragma unroll
        for (int nd = 0; nd < 4; ++nd)
          o[mi][nd] = __builtin_amdgcn_mfma_f32_16x16x32_bf16(pf[mi], vf[nd], o[mi][nd], 0, 0, 0);
    }
    __builtin_amdgcn_s_setprio(0);
  }

  // ---- epilogue: normalize, sigmoid-gate, store
#pragma unroll
  for (int mi = 0; mi < 2; ++mi)
#pragma unroll
    for (int r = 0; r < 4; ++r) {
      float inv = 1.f / lr[mi][r];
      int m = (int)((size_t)b * SS) + qs0 + mi * 16 + ((ln >> 4) << 2) + r;
#pragma unroll
      for (int nd = 0; nd < 4; ++nd) {
        int col = h * DD + nd * 16 + (ln & 15);
        float gv = (float)G[(size_t)m * EE + col];
        float sig = 1.f / (1.f + __expf(-gv));
        AO[(size_t)m * EE + col] = (bf16_t)((o[mi][nd][r] * inv) * sig);
      }
    }
}

extern "C" void kernel_launch(void* const* d_in, const int* in_sizes, int n_in,
                              void* d_out, int out_size, void* d_ws, size_t ws_size,
                              hipStream_t stream) {
  const float* x = (const float*)d_in[0];
  const float* Wq = (const float*)d_in[1];
  const float* Wk = (const float*)d_in[2];
  const float* Wv = (const float*)d_in[3];
  const float* Wg = (const float*)d_in[4];
  const float* Wo = (const float*)d_in[5];
  const float* cosp = (const float*)d_in[6];
  const float* sinp = (const float*)d_in[7];
  float* out = (float*)d_out;

  char* ws = (char*)d_ws;
  bf16_t* XB = (bf16_t*)(ws);                       // 16MB: x bf16; reused as gated AO
  bf16_t* WT = (bf16_t*)(ws + (16ll << 20));        // 10MB: [5][1024][1024] W^T bf16 (q,k,v,g,o)
  bf16_t* QB = (bf16_t*)(ws + (26ll << 20));        // 16MB: Q (unroped)
  bf16_t* KB = (bf16_t*)(ws + (42ll << 20));        // 16MB: K (unroped)
  bf16_t* VT = (bf16_t*)(ws + (58ll << 20));        // 16MB: V transposed [B][H][D][S]
  bf16_t* GB = (bf16_t*)(ws + (74ll << 20));        // 16MB: gate
  bf16_t* AO = XB;                                  // gated attention output reuses XB region

  const int n8 = MM * EE / 8;  // 1048576
  cvt_kernel<<<n8 / 256, 256, 0, stream>>>(x, XB, n8);
  wt_kernel<<<dim3(32, 32, 5), 256, 0, stream>>>(Wq, Wk, Wv, Wg, Wo, WT);
  gemm_bt<0><<<dim3(MM / 128, 4 * EE / 128), 256, 0, stream>>>(XB, WT, QB);
  attn_kernel<<<1024, 256, 0, stream>>>(QB, KB, VT, GB, cosp, sinp, AO);
  gemm_bt<1><<<dim3(MM / 128, EE / 128), 256, 0, stream>>>(AO, WT + (size_t)4 * EE * EE, out);
}

// Round 8
// 155.589 us; speedup vs baseline: 1.2263x; 1.0529x over previous
//
#include <hip/hip_runtime.h>
#include <hip/hip_bf16.h>
#include <stdint.h>

typedef __bf16 bf16_t;
typedef __bf16 bf16x8 __attribute__((ext_vector_type(8)));
typedef float f32x4 __attribute__((ext_vector_type(4)));

#define DEVI __device__ __forceinline__

constexpr int BB = 2;       // batch
constexpr int SS = 4096;    // seq
constexpr int EE = 1024;    // embed
constexpr int HH = 16;      // heads
constexpr int DD = 64;      // head dim
constexpr int MM = BB * SS; // 8192 token rows

// async global->LDS, 16B per lane; LDS dest must be wave-uniform base (HW adds lane*16)
DEVI void gload16(const void* g, void* l) {
  __builtin_amdgcn_global_load_lds(
      (const __attribute__((address_space(1))) void*)g,
      (__attribute__((address_space(3))) void*)l, 16, 0, 0);
}

// ---------------- f32 -> bf16 convert (vectorized 8/thread) ----------------
__global__ void cvt_kernel(const float* __restrict__ in, bf16_t* __restrict__ out, int n8) {
  int i = blockIdx.x * 256 + threadIdx.x;
  if (i >= n8) return;
  const float* p = in + (size_t)i * 8;
  bf16x8 o;
#pragma unroll
  for (int j = 0; j < 8; ++j) o[j] = (bf16_t)p[j];
  *(bf16x8*)(out + (size_t)i * 8) = o;
}

// ---------------- weight transpose + cvt: W[k][n] f32 -> WT[n][k] bf16 ----------------
__global__ void wt_kernel(const float* __restrict__ w0, const float* __restrict__ w1,
                          const float* __restrict__ w2, const float* __restrict__ w3,
                          const float* __restrict__ w4, bf16_t* __restrict__ out) {
  __shared__ float tile[32][33];
  const float* Wsel = blockIdx.z == 0 ? w0 : blockIdx.z == 1 ? w1 :
                      blockIdx.z == 2 ? w2 : blockIdx.z == 3 ? w3 : w4;
  bf16_t* O = out + (size_t)blockIdx.z * EE * EE;
  int n0 = blockIdx.x * 32, k0 = blockIdx.y * 32;
  int tx = threadIdx.x & 31, ty = threadIdx.x >> 5;
#pragma unroll
  for (int i = 0; i < 4; ++i)
    tile[ty + i * 8][tx] = Wsel[(size_t)(k0 + ty + i * 8) * EE + n0 + tx];
  __syncthreads();
#pragma unroll
  for (int i = 0; i < 4; ++i)
    O[(size_t)(n0 + ty + i * 8) * EE + k0 + tx] = (bf16_t)tile[tx][ty + i * 8];
}

// ---------------- GEMM: C[M][N] = A[M][K] @ Bt[N][K]^T, 128x128 tile, BK=64 ----------------
// EXACT r1 form (measured 83.3 us / VGPR 80 / FETCH 56.4MB on this shape): runtime Kdim,
// per-element widx epilogue. Do not "clean up" — r6/r7 variants measured 95 us.
// MODE 0: bf16 out into 4 contiguous regions (Q,K,Vt,G); V (widx==2) transposed [B][H][D][S]
// MODE 1: f32 out [M][1024]
template <int MODE>
__global__ __launch_bounds__(256) void gemm_bt(const bf16_t* __restrict__ A,
                                               const bf16_t* __restrict__ Bt,
                                               void* __restrict__ Cout, int Kdim) {
  __shared__ bf16_t Al[128 * 64];
  __shared__ bf16_t Bl[128 * 64];
  const int m0 = blockIdx.x * 128;
  const int n0 = blockIdx.y * 128;
  const int tid = threadIdx.x;
  const int wv = tid >> 6, ln = tid & 63;
  const int wm = wv >> 1, wn = wv & 1;
  f32x4 acc[4][4] = {};

  for (int k0 = 0; k0 < Kdim; k0 += 64) {
    __syncthreads();  // prior iter's LDS readers done before overwrite
#pragma unroll
    for (int i = 0; i < 4; ++i) {
      int slot = i * 256 + wv * 64 + ln;  // 16B slots, 8 per 128B row
      int r = slot >> 3, c = slot & 7;
      int cs = c ^ (r & 7);  // inverse-swizzled source chunk (linear LDS dest)
      gload16(A + (size_t)(m0 + r) * Kdim + k0 + cs * 8, Al + (size_t)(i * 256 + wv * 64) * 8);
      gload16(Bt + (size_t)(n0 + r) * Kdim + k0 + cs * 8, Bl + (size_t)(i * 256 + wv * 64) * 8);
    }
    __syncthreads();  // compiler drains vmcnt(0) before barrier
#pragma unroll
    for (int kk = 0; kk < 2; ++kk) {
      bf16x8 af[4], bfr[4];
#pragma unroll
      for (int mi = 0; mi < 4; ++mi) {
        int row = wm * 64 + mi * 16 + (ln & 15);
        int ch = (kk * 4 + (ln >> 4)) ^ (row & 7);
        af[mi] = *(const bf16x8*)(Al + row * 64 + ch * 8);
      }
#pragma unroll
      for (int ni = 0; ni < 4; ++ni) {
        int row = wn * 64 + ni * 16 + (ln & 15);
        int ch = (kk * 4 + (ln >> 4)) ^ (row & 7);
        bfr[ni] = *(const bf16x8*)(Bl + row * 64 + ch * 8);
      }
#pragma unroll
      for (int mi = 0; mi < 4; ++mi)
#pragma unroll
        for (int ni = 0; ni < 4; ++ni)
          acc[mi][ni] = __builtin_amdgcn_mfma_f32_16x16x32_bf16(af[mi], bfr[ni], acc[mi][ni], 0, 0, 0);
    }
  }

  if (MODE == 0) {
    bf16_t* Obase = (bf16_t*)Cout;
#pragma unroll
    for (int mi = 0; mi < 4; ++mi) {
#pragma unroll
      for (int ni = 0; ni < 4; ++ni) {
        int row = m0 + wm * 64 + mi * 16 + ((ln >> 4) << 2);  // + reg
        int col = n0 + wn * 64 + ni * 16 + (ln & 15);
        int widx = col >> 10, ncol = col & 1023;
        bf16_t* W = Obase + (size_t)widx * MM * EE;
        if (widx == 2) {  // V: write transposed [B][H][D][S]
          int h = ncol >> 6, d = ncol & 63;
          int b = row >> 12, s = row & (SS - 1);
          bf16_t* p = W + (((size_t)b * HH + h) * DD + d) * SS + s;
#pragma unroll
          for (int r = 0; r < 4; ++r) p[r] = (bf16_t)acc[mi][ni][r];
        } else {
          bf16_t* p = W + (size_t)row * EE + ncol;
#pragma unroll
          for (int r = 0; r < 4; ++r) p[(size_t)r * EE] = (bf16_t)acc[mi][ni][r];
        }
      }
    }
  } else {
    float* O = (float*)Cout;
#pragma unroll
    for (int mi = 0; mi < 4; ++mi)
#pragma unroll
      for (int ni = 0; ni < 4; ++ni) {
        int row = m0 + wm * 64 + mi * 16 + ((ln >> 4) << 2);
        int col = n0 + wn * 64 + ni * 16 + (ln & 15);
#pragma unroll
        for (int r = 0; r < 4; ++r) O[(size_t)(row + r) * EE + col] = acc[mi][ni][r];
      }
  }
}

// ---------------- block-diagonal attention + fused RoPE + fused sigmoid gate ----------------
// grid: 1024 half-blocks (2 per (b,sb,h)); 4 waves x 32 q-rows; 2 blocks/CU co-resident.
// Full 256-key staging: K (roped in LDS once) + V^T staged up front, exact softmax
// (no online rescale), PV via per-wave P-LDS chunks. Only 2 barriers per block.
__global__ __launch_bounds__(256, 2) void attn_kernel(const bf16_t* __restrict__ Q,
                                                      const bf16_t* __restrict__ Kc,
                                                      const bf16_t* __restrict__ Vt,
                                                      const bf16_t* __restrict__ G,
                                                      const float* __restrict__ cosp,
                                                      const float* __restrict__ sinp,
                                                      bf16_t* __restrict__ AO) {
  __shared__ bf16_t Kl[256 * 64];   // 32KB: K rows (roped), row-swizzled chunks
  __shared__ bf16_t Vl[64 * 256];   // 32KB: V^T [d][s], chunk-swizzle c^((d&7)<<2)
  __shared__ bf16_t Pl[4][32 * 64]; // 16KB: per-wave P chunk
  const int id = blockIdx.x;
  const int swz = (id & 7) * 128 + (id >> 3);  // XCD swizzle: half-block pairs share an XCD
  const int half = swz & 1, ab = swz >> 1;
  const int h = ab & 15, sb = (ab >> 4) & 15, b = ab >> 8;
  const int tid = threadIdx.x, wv = tid >> 6, ln = tid & 63;
  const int qs0 = sb * 256 + half * 128 + wv * 32;  // this wave's 32 q-rows (seq index)

  // ---- stage full K (8 groups) + full V^T (8 groups): 16 gload16/thread
  {
    const bf16_t* Kbase = Kc + ((size_t)b * SS + sb * 256) * EE + h * DD;
    int kr = wv * 8 + (ln >> 3), kc8 = ln & 7;
#pragma unroll
    for (int g = 0; g < 8; ++g) {
      int r = g * 32 + kr, cs = kc8 ^ (r & 7);
      gload16(Kbase + (size_t)r * EE + cs * 8, &Kl[g * 2048 + wv * 512]);
    }
    const bf16_t* Vbase = Vt + ((size_t)b * HH + h) * DD * SS + sb * 256;
    int vr = wv * 2 + (ln >> 5), vc = ln & 31;
#pragma unroll
    for (int g = 0; g < 8; ++g) {
      int r = g * 8 + vr, cs = vc ^ ((r & 7) << 2);
      gload16(Vbase + (size_t)r * SS + cs * 8, &Vl[g * 2048 + wv * 512]);
    }
  }
  __syncthreads();  // drains all gloads

  // ---- K-rope in LDS: 256 threads x 4 rows each; octet pair d <-> d+32
  {
    int c_ = tid & 3;
#pragma unroll
    for (int rr = 0; rr < 4; ++rr) {
      int r_ = rr * 64 + (tid >> 2);
      int ks = sb * 256 + r_;
      int chl = ((c_ ^ (r_ & 7)) << 3), chh = (((c_ ^ 4) ^ (r_ & 7)) << 3);
      bf16x8 lo8 = *(bf16x8*)&Kl[r_ * 64 + chl];
      bf16x8 hi8 = *(bf16x8*)&Kl[r_ * 64 + chh];
      float cl[8], sl[8], chv[8], shv[8];
      *(f32x4*)&cl[0] = *(const f32x4*)&cosp[ks * DD + c_ * 8];
      *(f32x4*)&cl[4] = *(const f32x4*)&cosp[ks * DD + c_ * 8 + 4];
      *(f32x4*)&chv[0] = *(const f32x4*)&cosp[ks * DD + c_ * 8 + 32];
      *(f32x4*)&chv[4] = *(const f32x4*)&cosp[ks * DD + c_ * 8 + 36];
      *(f32x4*)&sl[0] = *(const f32x4*)&sinp[ks * DD + c_ * 8];
      *(f32x4*)&sl[4] = *(const f32x4*)&sinp[ks * DD + c_ * 8 + 4];
      *(f32x4*)&shv[0] = *(const f32x4*)&sinp[ks * DD + c_ * 8 + 32];
      *(f32x4*)&shv[4] = *(const f32x4*)&sinp[ks * DD + c_ * 8 + 36];
      bf16x8 olo, ohi;
#pragma unroll
      for (int j = 0; j < 8; ++j) {
        float lo = (float)lo8[j], hi = (float)hi8[j];
        olo[j] = (bf16_t)(lo * cl[j] - hi * sl[j]);
        ohi[j] = (bf16_t)(hi * chv[j] + lo * shv[j]);
      }
      *(bf16x8*)&Kl[r_ * 64 + chl] = olo;
      *(bf16x8*)&Kl[r_ * 64 + chh] = ohi;
    }
  }

  // ---- Q fragments + in-register RoPE (overlaps rope/barrier latency)
  bf16x8 qf[2][2];
  const int d0 = (ln >> 4) << 3;
#pragma unroll
  for (int mi = 0; mi < 2; ++mi) {
    int qs = qs0 + mi * 16 + (ln & 15);
    const bf16_t* qp = Q + ((size_t)b * SS + qs) * EE + h * DD;
    qf[mi][0] = *(const bf16x8*)(qp + d0);
    qf[mi][1] = *(const bf16x8*)(qp + 32 + d0);
    float cl[8], sl[8], chv[8], shv[8];
    *(f32x4*)&cl[0] = *(const f32x4*)&cosp[qs * DD + d0];
    *(f32x4*)&cl[4] = *(const f32x4*)&cosp[qs * DD + d0 + 4];
    *(f32x4*)&chv[0] = *(const f32x4*)&cosp[qs * DD + d0 + 32];
    *(f32x4*)&chv[4] = *(const f32x4*)&cosp[qs * DD + d0 + 36];
    *(f32x4*)&sl[0] = *(const f32x4*)&sinp[qs * DD + d0];
    *(f32x4*)&sl[4] = *(const f32x4*)&sinp[qs * DD + d0 + 4];
    *(f32x4*)&shv[0] = *(const f32x4*)&sinp[qs * DD + d0 + 32];
    *(f32x4*)&shv[4] = *(const f32x4*)&sinp[qs * DD + d0 + 36];
#pragma unroll
    for (int j = 0; j < 8; ++j) {
      float lo = (float)qf[mi][0][j], hi = (float)qf[mi][1][j];
      qf[mi][0][j] = (bf16_t)(lo * cl[j] - hi * sl[j]);
      qf[mi][1][j] = (bf16_t)(hi * chv[j] + lo * shv[j]);
    }
  }
  __syncthreads();  // roped K visible to all waves

  // ---- QK^T: full S[32q][256k] in registers (sc[2][16] f32x4 = 128 VGPR)
  f32x4 sc[2][16];
#pragma unroll
  for (int mi = 0; mi < 2; ++mi)
#pragma unroll
    for (int ni = 0; ni < 16; ++ni) sc[mi][ni] = f32x4{0.f, 0.f, 0.f, 0.f};
  __builtin_amdgcn_s_setprio(1);
#pragma unroll
  for (int kk = 0; kk < 2; ++kk) {
#pragma unroll
    for (int ni = 0; ni < 16; ++ni) {
      int row = ni * 16 + (ln & 15);
      int ch = (kk * 4 + (ln >> 4)) ^ (row & 7);
      bf16x8 kf = *(const bf16x8*)(&Kl[row * 64 + ch * 8]);
#pragma unroll
      for (int mi = 0; mi < 2; ++mi)
        sc[mi][ni] = __builtin_amdgcn_mfma_f32_16x16x32_bf16(qf[mi][kk], kf, sc[mi][ni], 0, 0, 0);
    }
  }
  __builtin_amdgcn_s_setprio(0);

  // ---- exact softmax (one pass; reduce in-lane 16, then across ln&15 lanes)
  float lr[2][4];
#pragma unroll
  for (int mi = 0; mi < 2; ++mi) {
#pragma unroll
    for (int r = 0; r < 4; ++r) {
      float mx = -1e30f;
#pragma unroll
      for (int ni = 0; ni < 16; ++ni) mx = fmaxf(mx, sc[mi][ni][r] * 0.125f);
#pragma unroll
      for (int d = 1; d < 16; d <<= 1) mx = fmaxf(mx, __shfl_xor(mx, d));
      float rs = 0.f;
#pragma unroll
      for (int ni = 0; ni < 16; ++ni) {
        float p = __expf(sc[mi][ni][r] * 0.125f - mx);
        sc[mi][ni][r] = p;
        rs += p;
      }
#pragma unroll
      for (int d = 1; d < 16; d <<= 1) rs += __shfl_xor(rs, d);
      lr[mi][r] = rs;
    }
  }

  // ---- PV: per 64-k chunk through per-wave P-LDS (no barriers; per-wave RAW via lgkm)
  f32x4 o[2][4] = {};
  bf16_t* P = Pl[wv];
#pragma unroll
  for (int kc = 0; kc < 4; ++kc) {
#pragma unroll
    for (int mi = 0; mi < 2; ++mi)
#pragma unroll
      for (int nq = 0; nq < 4; ++nq)
#pragma unroll
        for (int r = 0; r < 4; ++r) {
          int row = mi * 16 + ((ln >> 4) << 2) + r;
          int col = nq * 16 + (ln & 15);
          P[row * 64 + (col ^ ((row & 7) << 3))] = (bf16_t)sc[mi][kc * 4 + nq][r];
        }
    __builtin_amdgcn_s_setprio(1);
#pragma unroll
    for (int kk = 0; kk < 2; ++kk) {
      bf16x8 pf[2], vf[4];
#pragma unroll
      for (int mi = 0; mi < 2; ++mi) {
        int row = mi * 16 + (ln & 15);
        int ch = (kk * 4 + (ln >> 4)) ^ (row & 7);
        pf[mi] = *(const bf16x8*)(P + row * 64 + ch * 8);
      }
#pragma unroll
      for (int nd = 0; nd < 4; ++nd) {
        int d = nd * 16 + (ln & 15);
        int c = (kc * 8 + kk * 4 + (ln >> 4)) ^ ((d & 7) << 2);
        vf[nd] = *(const bf16x8*)(&Vl[d * 256 + c * 8]);
      }
#pragma unroll
      for (int mi = 0; mi < 2; ++mi)
#pragma unroll
        for (int nd = 0; nd < 4; ++nd)
          o[mi][nd] = __builtin_amdgcn_mfma_f32_16x16x32_bf16(pf[mi], vf[nd], o[mi][nd], 0, 0, 0);
    }
    __builtin_amdgcn_s_setprio(0);
  }

  // ---- epilogue: normalize, sigmoid-gate, store
#pragma unroll
  for (int mi = 0; mi < 2; ++mi)
#pragma unroll
    for (int r = 0; r < 4; ++r) {
      float inv = 1.f / lr[mi][r];
      int m = (int)((size_t)b * SS) + qs0 + mi * 16 + ((ln >> 4) << 2) + r;
#pragma unroll
      for (int nd = 0; nd < 4; ++nd) {
        int col = h * DD + nd * 16 + (ln & 15);
        float gv = (float)G[(size_t)m * EE + col];
        float sig = 1.f / (1.f + __expf(-gv));
        AO[(size_t)m * EE + col] = (bf16_t)((o[mi][nd][r] * inv) * sig);
      }
    }
}

extern "C" void kernel_launch(void* const* d_in, const int* in_sizes, int n_in,
                              void* d_out, int out_size, void* d_ws, size_t ws_size,
                              hipStream_t stream) {
  const float* x = (const float*)d_in[0];
  const float* Wq = (const float*)d_in[1];
  const float* Wk = (const float*)d_in[2];
  const float* Wv = (const float*)d_in[3];
  const float* Wg = (const float*)d_in[4];
  const float* Wo = (const float*)d_in[5];
  const float* cosp = (const float*)d_in[6];
  const float* sinp = (const float*)d_in[7];
  float* out = (float*)d_out;

  char* ws = (char*)d_ws;
  bf16_t* XB = (bf16_t*)(ws);                       // 16MB: x bf16; reused as gated AO
  bf16_t* WT = (bf16_t*)(ws + (16ll << 20));        // 10MB: [5][1024][1024] W^T bf16 (q,k,v,g,o)
  bf16_t* QB = (bf16_t*)(ws + (26ll << 20));        // 16MB: Q (unroped)
  bf16_t* KB = (bf16_t*)(ws + (42ll << 20));        // 16MB: K (unroped)
  bf16_t* VT = (bf16_t*)(ws + (58ll << 20));        // 16MB: V transposed [B][H][D][S]
  bf16_t* GB = (bf16_t*)(ws + (74ll << 20));        // 16MB: gate
  bf16_t* AO = XB;                                  // gated attention output reuses XB region

  const int n8 = MM * EE / 8;  // 1048576
  cvt_kernel<<<n8 / 256, 256, 0, stream>>>(x, XB, n8);
  wt_kernel<<<dim3(32, 32, 5), 256, 0, stream>>>(Wq, Wk, Wv, Wg, Wo, WT);
  gemm_bt<0><<<dim3(MM / 128, 4 * EE / 128), 256, 0, stream>>>(XB, WT, QB, EE);
  attn_kernel<<<1024, 256, 0, stream>>>(QB, KB, VT, GB, cosp, sinp, AO);
  gemm_bt<1><<<dim3(MM / 128, EE / 128), 256, 0, stream>>>(AO, WT + (size_t)4 * EE * EE, out, EE);
}

// Round 9
// 155.011 us; speedup vs baseline: 1.2308x; 1.0037x over previous
//
#include <hip/hip_runtime.h>
#include <hip/hip_bf16.h>
#include <stdint.h>

typedef __bf16 bf16_t;
typedef __bf16 bf16x8 __attribute__((ext_vector_type(8)));
typedef float f32x4 __attribute__((ext_vector_type(4)));

#define DEVI __device__ __forceinline__

constexpr int BB = 2;       // batch
constexpr int SS = 4096;    // seq
constexpr int EE = 1024;    // embed
constexpr int HH = 16;      // heads
constexpr int DD = 64;      // head dim
constexpr int MM = BB * SS; // 8192 token rows

// async global->LDS, 16B per lane; LDS dest must be wave-uniform base (HW adds lane*16)
DEVI void gload16(const void* g, void* l) {
  __builtin_amdgcn_global_load_lds(
      (const __attribute__((address_space(1))) void*)g,
      (__attribute__((address_space(3))) void*)l, 16, 0, 0);
}

// ---------------- f32 -> bf16 convert (vectorized 8/thread) ----------------
__global__ void cvt_kernel(const float* __restrict__ in, bf16_t* __restrict__ out, int n8) {
  int i = blockIdx.x * 256 + threadIdx.x;
  if (i >= n8) return;
  const float* p = in + (size_t)i * 8;
  bf16x8 o;
#pragma unroll
  for (int j = 0; j < 8; ++j) o[j] = (bf16_t)p[j];
  *(bf16x8*)(out + (size_t)i * 8) = o;
}

// ---------------- weight transpose + cvt: W[k][n] f32 -> WT[n][k] bf16 ----------------
__global__ void wt_kernel(const float* __restrict__ w0, const float* __restrict__ w1,
                          const float* __restrict__ w2, const float* __restrict__ w3,
                          const float* __restrict__ w4, bf16_t* __restrict__ out) {
  __shared__ float tile[32][33];
  const float* Wsel = blockIdx.z == 0 ? w0 : blockIdx.z == 1 ? w1 :
                      blockIdx.z == 2 ? w2 : blockIdx.z == 3 ? w3 : w4;
  bf16_t* O = out + (size_t)blockIdx.z * EE * EE;
  int n0 = blockIdx.x * 32, k0 = blockIdx.y * 32;
  int tx = threadIdx.x & 31, ty = threadIdx.x >> 5;
#pragma unroll
  for (int i = 0; i < 4; ++i)
    tile[ty + i * 8][tx] = Wsel[(size_t)(k0 + ty + i * 8) * EE + n0 + tx];
  __syncthreads();
#pragma unroll
  for (int i = 0; i < 4; ++i)
    O[(size_t)(n0 + ty + i * 8) * EE + k0 + tx] = (bf16_t)tile[tx][ty + i * 8];
}

// ---------------- GEMM: C[M][N] = A[M][K] @ Bt[N][K]^T, 128x128 tile, BK=64 ----------------
// EXACT r1 form (measured 81.9-83.3 us / VGPR 80 / FETCH 56.4MB): runtime Kdim,
// per-element widx epilogue. FROZEN — r3-r7 "improvements" all measured 93-100 us.
// MODE 0: bf16 out into 4 contiguous regions (Q,K,Vt,G); V (widx==2) transposed [B][H][D][S]
// MODE 1: f32 out [M][1024]
template <int MODE>
__global__ __launch_bounds__(256) void gemm_bt(const bf16_t* __restrict__ A,
                                               const bf16_t* __restrict__ Bt,
                                               void* __restrict__ Cout, int Kdim) {
  __shared__ bf16_t Al[128 * 64];
  __shared__ bf16_t Bl[128 * 64];
  const int m0 = blockIdx.x * 128;
  const int n0 = blockIdx.y * 128;
  const int tid = threadIdx.x;
  const int wv = tid >> 6, ln = tid & 63;
  const int wm = wv >> 1, wn = wv & 1;
  f32x4 acc[4][4] = {};

  for (int k0 = 0; k0 < Kdim; k0 += 64) {
    __syncthreads();  // prior iter's LDS readers done before overwrite
#pragma unroll
    for (int i = 0; i < 4; ++i) {
      int slot = i * 256 + wv * 64 + ln;  // 16B slots, 8 per 128B row
      int r = slot >> 3, c = slot & 7;
      int cs = c ^ (r & 7);  // inverse-swizzled source chunk (linear LDS dest)
      gload16(A + (size_t)(m0 + r) * Kdim + k0 + cs * 8, Al + (size_t)(i * 256 + wv * 64) * 8);
      gload16(Bt + (size_t)(n0 + r) * Kdim + k0 + cs * 8, Bl + (size_t)(i * 256 + wv * 64) * 8);
    }
    __syncthreads();  // compiler drains vmcnt(0) before barrier
#pragma unroll
    for (int kk = 0; kk < 2; ++kk) {
      bf16x8 af[4], bfr[4];
#pragma unroll
      for (int mi = 0; mi < 4; ++mi) {
        int row = wm * 64 + mi * 16 + (ln & 15);
        int ch = (kk * 4 + (ln >> 4)) ^ (row & 7);
        af[mi] = *(const bf16x8*)(Al + row * 64 + ch * 8);
      }
#pragma unroll
      for (int ni = 0; ni < 4; ++ni) {
        int row = wn * 64 + ni * 16 + (ln & 15);
        int ch = (kk * 4 + (ln >> 4)) ^ (row & 7);
        bfr[ni] = *(const bf16x8*)(Bl + row * 64 + ch * 8);
      }
#pragma unroll
      for (int mi = 0; mi < 4; ++mi)
#pragma unroll
        for (int ni = 0; ni < 4; ++ni)
          acc[mi][ni] = __builtin_amdgcn_mfma_f32_16x16x32_bf16(af[mi], bfr[ni], acc[mi][ni], 0, 0, 0);
    }
  }

  if (MODE == 0) {
    bf16_t* Obase = (bf16_t*)Cout;
#pragma unroll
    for (int mi = 0; mi < 4; ++mi) {
#pragma unroll
      for (int ni = 0; ni < 4; ++ni) {
        int row = m0 + wm * 64 + mi * 16 + ((ln >> 4) << 2);  // + reg
        int col = n0 + wn * 64 + ni * 16 + (ln & 15);
        int widx = col >> 10, ncol = col & 1023;
        bf16_t* W = Obase + (size_t)widx * MM * EE;
        if (widx == 2) {  // V: write transposed [B][H][D][S]
          int h = ncol >> 6, d = ncol & 63;
          int b = row >> 12, s = row & (SS - 1);
          bf16_t* p = W + (((size_t)b * HH + h) * DD + d) * SS + s;
#pragma unroll
          for (int r = 0; r < 4; ++r) p[r] = (bf16_t)acc[mi][ni][r];
        } else {
          bf16_t* p = W + (size_t)row * EE + ncol;
#pragma unroll
          for (int r = 0; r < 4; ++r) p[(size_t)r * EE] = (bf16_t)acc[mi][ni][r];
        }
      }
    }
  } else {
    float* O = (float*)Cout;
#pragma unroll
    for (int mi = 0; mi < 4; ++mi)
#pragma unroll
      for (int ni = 0; ni < 4; ++ni) {
        int row = m0 + wm * 64 + mi * 16 + ((ln >> 4) << 2);
        int col = n0 + wn * 64 + ni * 16 + (ln & 15);
#pragma unroll
        for (int r = 0; r < 4; ++r) O[(size_t)(row + r) * EE + col] = acc[mi][ni][r];
      }
  }
}

// ---------------- block-diagonal attention + fused RoPE + fused sigmoid gate ----------------
// grid: 1024 half-blocks (2 per (b,sb,h)); 4 waves x 32 q-rows; 2 blocks/CU co-resident.
// Full 256-key staging, exact softmax, PV via per-wave P-LDS.
// r9: G prefetched to regs at entry; Q/cos/sin loads hoisted before first sync;
//     vectorized epilogue via o-transpose through freed Kl (c^(row&7) 16B-chunk swizzle).
__global__ __launch_bounds__(256, 2) void attn_kernel(const bf16_t* __restrict__ Q,
                                                      const bf16_t* __restrict__ Kc,
                                                      const bf16_t* __restrict__ Vt,
                                                      const bf16_t* __restrict__ G,
                                                      const float* __restrict__ cosp,
                                                      const float* __restrict__ sinp,
                                                      bf16_t* __restrict__ AO) {
  __shared__ bf16_t Kl[256 * 64];   // 32KB: K rows (roped); reused as f32 o-transpose buffer
  __shared__ bf16_t Vl[64 * 256];   // 32KB: V^T [d][s], chunk-swizzle c^((d&7)<<2)
  __shared__ bf16_t Pl[4][32 * 64]; // 16KB: per-wave P chunk; head 128B reused for lr
  const int id = blockIdx.x;
  const int swz = (id & 7) * 128 + (id >> 3);  // XCD swizzle: half-block pairs share an XCD
  const int half = swz & 1, ab = swz >> 1;
  const int h = ab & 15, sb = (ab >> 4) & 15, b = ab >> 8;
  const int tid = threadIdx.x, wv = tid >> 6, ln = tid & 63;
  const int qs0 = sb * 256 + half * 128 + wv * 32;  // this wave's 32 q-rows (seq index)

  // ---- stage full K (8 groups) + full V^T (8 groups): 16 gload16/thread
  {
    const bf16_t* Kbase = Kc + ((size_t)b * SS + sb * 256) * EE + h * DD;
    int kr = wv * 8 + (ln >> 3), kc8 = ln & 7;
#pragma unroll
    for (int g = 0; g < 8; ++g) {
      int r = g * 32 + kr, cs = kc8 ^ (r & 7);
      gload16(Kbase + (size_t)r * EE + cs * 8, &Kl[g * 2048 + wv * 512]);
    }
    const bf16_t* Vbase = Vt + ((size_t)b * HH + h) * DD * SS + sb * 256;
    int vr = wv * 2 + (ln >> 5), vc = ln & 31;
#pragma unroll
    for (int g = 0; g < 8; ++g) {
      int r = g * 8 + vr, cs = vc ^ ((r & 7) << 2);
      gload16(Vbase + (size_t)r * SS + cs * 8, &Vl[g * 2048 + wv * 512]);
    }
  }

  // ---- prefetch G for the post-transpose epilogue (issued under staging latency)
  const int erow = ln >> 1, ehf = ln & 1;           // lane's epilogue row / 32-col half
  const int em = b * SS + qs0 + erow;               // global token row
  bf16x8 gpre[4];
  {
    const bf16_t* gp = G + (size_t)em * EE + h * DD + ehf * 32;
#pragma unroll
    for (int i = 0; i < 4; ++i) gpre[i] = *(const bf16x8*)(gp + i * 8);
  }

  // ---- Q fragments + cos/sin loads (issued before first sync; compute after)
  bf16x8 qraw[2][2];
  float cl[2][8], sl[2][8], chv[2][8], shv[2][8];
  const int d0 = (ln >> 4) << 3;
#pragma unroll
  for (int mi = 0; mi < 2; ++mi) {
    int qs = qs0 + mi * 16 + (ln & 15);
    const bf16_t* qp = Q + ((size_t)b * SS + qs) * EE + h * DD;
    qraw[mi][0] = *(const bf16x8*)(qp + d0);
    qraw[mi][1] = *(const bf16x8*)(qp + 32 + d0);
    *(f32x4*)&cl[mi][0] = *(const f32x4*)&cosp[qs * DD + d0];
    *(f32x4*)&cl[mi][4] = *(const f32x4*)&cosp[qs * DD + d0 + 4];
    *(f32x4*)&chv[mi][0] = *(const f32x4*)&cosp[qs * DD + d0 + 32];
    *(f32x4*)&chv[mi][4] = *(const f32x4*)&cosp[qs * DD + d0 + 36];
    *(f32x4*)&sl[mi][0] = *(const f32x4*)&sinp[qs * DD + d0];
    *(f32x4*)&sl[mi][4] = *(const f32x4*)&sinp[qs * DD + d0 + 4];
    *(f32x4*)&shv[mi][0] = *(const f32x4*)&sinp[qs * DD + d0 + 32];
    *(f32x4*)&shv[mi][4] = *(const f32x4*)&sinp[qs * DD + d0 + 36];
  }
  __syncthreads();  // drains all gloads (staging) + register loads

  // ---- Q RoPE in registers
  bf16x8 qf[2][2];
#pragma unroll
  for (int mi = 0; mi < 2; ++mi)
#pragma unroll
    for (int j = 0; j < 8; ++j) {
      float lo = (float)qraw[mi][0][j], hi = (float)qraw[mi][1][j];
      qf[mi][0][j] = (bf16_t)(lo * cl[mi][j] - hi * sl[mi][j]);
      qf[mi][1][j] = (bf16_t)(hi * chv[mi][j] + lo * shv[mi][j]);
    }

  // ---- K-rope in LDS: 256 threads x 4 rows each; octet pair d <-> d+32
  {
    int c_ = tid & 3;
#pragma unroll
    for (int rr = 0; rr < 4; ++rr) {
      int r_ = rr * 64 + (tid >> 2);
      int ks = sb * 256 + r_;
      int chl = ((c_ ^ (r_ & 7)) << 3), chh = (((c_ ^ 4) ^ (r_ & 7)) << 3);
      bf16x8 lo8 = *(bf16x8*)&Kl[r_ * 64 + chl];
      bf16x8 hi8 = *(bf16x8*)&Kl[r_ * 64 + chh];
      float kc_[8], ks_[8], kch[8], ksh[8];
      *(f32x4*)&kc_[0] = *(const f32x4*)&cosp[ks * DD + c_ * 8];
      *(f32x4*)&kc_[4] = *(const f32x4*)&cosp[ks * DD + c_ * 8 + 4];
      *(f32x4*)&kch[0] = *(const f32x4*)&cosp[ks * DD + c_ * 8 + 32];
      *(f32x4*)&kch[4] = *(const f32x4*)&cosp[ks * DD + c_ * 8 + 36];
      *(f32x4*)&ks_[0] = *(const f32x4*)&sinp[ks * DD + c_ * 8];
      *(f32x4*)&ks_[4] = *(const f32x4*)&sinp[ks * DD + c_ * 8 + 4];
      *(f32x4*)&ksh[0] = *(const f32x4*)&sinp[ks * DD + c_ * 8 + 32];
      *(f32x4*)&ksh[4] = *(const f32x4*)&sinp[ks * DD + c_ * 8 + 36];
      bf16x8 olo, ohi;
#pragma unroll
      for (int j = 0; j < 8; ++j) {
        float lo = (float)lo8[j], hi = (float)hi8[j];
        olo[j] = (bf16_t)(lo * kc_[j] - hi * ks_[j]);
        ohi[j] = (bf16_t)(hi * kch[j] + lo * ksh[j]);
      }
      *(bf16x8*)&Kl[r_ * 64 + chl] = olo;
      *(bf16x8*)&Kl[r_ * 64 + chh] = ohi;
    }
  }
  __syncthreads();  // roped K visible to all waves

  // ---- QK^T: full S[32q][256k] in registers (sc[2][16] f32x4 = 128 VGPR)
  f32x4 sc[2][16];
#pragma unroll
  for (int mi = 0; mi < 2; ++mi)
#pragma unroll
    for (int ni = 0; ni < 16; ++ni) sc[mi][ni] = f32x4{0.f, 0.f, 0.f, 0.f};
  __builtin_amdgcn_s_setprio(1);
#pragma unroll
  for (int kk = 0; kk < 2; ++kk) {
#pragma unroll
    for (int ni = 0; ni < 16; ++ni) {
      int row = ni * 16 + (ln & 15);
      int ch = (kk * 4 + (ln >> 4)) ^ (row & 7);
      bf16x8 kf = *(const bf16x8*)(&Kl[row * 64 + ch * 8]);
#pragma unroll
      for (int mi = 0; mi < 2; ++mi)
        sc[mi][ni] = __builtin_amdgcn_mfma_f32_16x16x32_bf16(qf[mi][kk], kf, sc[mi][ni], 0, 0, 0);
    }
  }
  __builtin_amdgcn_s_setprio(0);

  // ---- exact softmax (one pass; reduce in-lane 16, then across ln&15 lanes)
  float lr[2][4];
#pragma unroll
  for (int mi = 0; mi < 2; ++mi) {
#pragma unroll
    for (int r = 0; r < 4; ++r) {
      float mx = -1e30f;
#pragma unroll
      for (int ni = 0; ni < 16; ++ni) mx = fmaxf(mx, sc[mi][ni][r] * 0.125f);
#pragma unroll
      for (int d = 1; d < 16; d <<= 1) mx = fmaxf(mx, __shfl_xor(mx, d));
      float rs = 0.f;
#pragma unroll
      for (int ni = 0; ni < 16; ++ni) {
        float p = __expf(sc[mi][ni][r] * 0.125f - mx);
        sc[mi][ni][r] = p;
        rs += p;
      }
#pragma unroll
      for (int d = 1; d < 16; d <<= 1) rs += __shfl_xor(rs, d);
      lr[mi][r] = rs;
    }
  }

  // ---- PV: per 64-k chunk through per-wave P-LDS (no barriers; per-wave RAW via lgkm)
  f32x4 o[2][4] = {};
  bf16_t* P = Pl[wv];
#pragma unroll
  for (int kc = 0; kc < 4; ++kc) {
#pragma unroll
    for (int mi = 0; mi < 2; ++mi)
#pragma unroll
      for (int nq = 0; nq < 4; ++nq)
#pragma unroll
        for (int r = 0; r < 4; ++r) {
          int row = mi * 16 + ((ln >> 4) << 2) + r;
          int col = nq * 16 + (ln & 15);
          P[row * 64 + (col ^ ((row & 7) << 3))] = (bf16_t)sc[mi][kc * 4 + nq][r];
        }
    __builtin_amdgcn_s_setprio(1);
#pragma unroll
    for (int kk = 0; kk < 2; ++kk) {
      bf16x8 pf[2], vf[4];
#pragma unroll
      for (int mi = 0; mi < 2; ++mi) {
        int row = mi * 16 + (ln & 15);
        int ch = (kk * 4 + (ln >> 4)) ^ (row & 7);
        pf[mi] = *(const bf16x8*)(P + row * 64 + ch * 8);
      }
#pragma unroll
      for (int nd = 0; nd < 4; ++nd) {
        int d = nd * 16 + (ln & 15);
        int c = (kc * 8 + kk * 4 + (ln >> 4)) ^ ((d & 7) << 2);
        vf[nd] = *(const bf16x8*)(&Vl[d * 256 + c * 8]);
      }
#pragma unroll
      for (int mi = 0; mi < 2; ++mi)
#pragma unroll
        for (int nd = 0; nd < 4; ++nd)
          o[mi][nd] = __builtin_amdgcn_mfma_f32_16x16x32_bf16(pf[mi], vf[nd], o[mi][nd], 0, 0, 0);
    }
    __builtin_amdgcn_s_setprio(0);
  }

  // ---- epilogue: transpose o through freed Kl; vectorized gate+store
  __syncthreads();  // all waves past QK -> Kl safe to overwrite
  // lr -> per-wave Pl head (written by lanes ln&15==0; all 16 lanes of a group hold same value)
  float* lrT = (float*)Pl[wv];
  if ((ln & 15) == 0) {
#pragma unroll
    for (int mi = 0; mi < 2; ++mi)
#pragma unroll
      for (int r = 0; r < 4; ++r)
        lrT[mi * 16 + ((ln >> 4) << 2) + r] = lr[mi][r];
  }
  // o -> per-wave f32 [32 rows][16 chunks of 4], chunk swizzle c^(row&7)
  float* T = (float*)Kl + wv * 2048;
#pragma unroll
  for (int mi = 0; mi < 2; ++mi)
#pragma unroll
    for (int nd = 0; nd < 4; ++nd)
#pragma unroll
      for (int r = 0; r < 4; ++r) {
        int row = mi * 16 + ((ln >> 4) << 2) + r;
        int col = nd * 16 + (ln & 15);
        int c = col >> 2;
        T[row * 64 + ((c ^ (row & 7)) << 2) + (col & 3)] = o[mi][nd][r];
      }
  // lane owns (erow, 32-col half): 8x f32x4 LDS reads + 4x bf16x8 gate/store
  {
    float inv = 1.f / lrT[erow];
    f32x4 ov[8];
#pragma unroll
    for (int j = 0; j < 8; ++j) {
      int c = ehf * 8 + j;
      ov[j] = *(const f32x4*)&T[erow * 64 + ((c ^ (erow & 7)) << 2)];
    }
    bf16_t* ap = AO + (size_t)em * EE + h * DD + ehf * 32;
#pragma unroll
    for (int i = 0; i < 4; ++i) {
      bf16x8 outv;
#pragma unroll
      for (int j2 = 0; j2 < 8; ++j2) {
        float gv = (float)gpre[i][j2];
        float sig = 1.f / (1.f + __expf(-gv));
        outv[j2] = (bf16_t)(ov[i * 2 + (j2 >> 2)][j2 & 3] * inv * sig);
      }
      *(bf16x8*)(ap + i * 8) = outv;
    }
  }
}

extern "C" void kernel_launch(void* const* d_in, const int* in_sizes, int n_in,
                              void* d_out, int out_size, void* d_ws, size_t ws_size,
                              hipStream_t stream) {
  const float* x = (const float*)d_in[0];
  const float* Wq = (const float*)d_in[1];
  const float* Wk = (const float*)d_in[2];
  const float* Wv = (const float*)d_in[3];
  const float* Wg = (const float*)d_in[4];
  const float* Wo = (const float*)d_in[5];
  const float* cosp = (const float*)d_in[6];
  const float* sinp = (const float*)d_in[7];
  float* out = (float*)d_out;

  char* ws = (char*)d_ws;
  bf16_t* XB = (bf16_t*)(ws);                       // 16MB: x bf16; reused as gated AO
  bf16_t* WT = (bf16_t*)(ws + (16ll << 20));        // 10MB: [5][1024][1024] W^T bf16 (q,k,v,g,o)
  bf16_t* QB = (bf16_t*)(ws + (26ll << 20));        // 16MB: Q (unroped)
  bf16_t* KB = (bf16_t*)(ws + (42ll << 20));        // 16MB: K (unroped)
  bf16_t* VT = (bf16_t*)(ws + (58ll << 20));        // 16MB: V transposed [B][H][D][S]
  bf16_t* GB = (bf16_t*)(ws + (74ll << 20));        // 16MB: gate
  bf16_t* AO = XB;                                  // gated attention output reuses XB region

  const int n8 = MM * EE / 8;  // 1048576
  cvt_kernel<<<n8 / 256, 256, 0, stream>>>(x, XB, n8);
  wt_kernel<<<dim3(32, 32, 5), 256, 0, stream>>>(Wq, Wk, Wv, Wg, Wo, WT);
  gemm_bt<0><<<dim3(MM / 128, 4 * EE / 128), 256, 0, stream>>>(XB, WT, QB, EE);
  attn_kernel<<<1024, 256, 0, stream>>>(QB, KB, VT, GB, cosp, sinp, AO);
  gemm_bt<1><<<dim3(MM / 128, EE / 128), 256, 0, stream>>>(AO, WT + (size_t)4 * EE * EE, out, EE);
}